// Round 5
// baseline (799.771 us; speedup 1.0000x reference)
//
#include <hip/hip_runtime.h>
#include <hip/hip_bf16.h>
#include <math.h>

// ---------------------------------------------------------------------------
// Mamba2 mixer forward, MI355X. Round 10: best-of-both GEMMs + yoff/ydiag fuse.
// R9: 733us. 2ph in-proj regressed (170 vs 8ph's 137; 128^2 2-barrier family
// ceiling ~850TF) but 2ph out-proj + no-mop-up won net -34. Changes:
//  - in-proj: 8ph 256^2 for cols 0..8191 (measured 137us) + 2ph tail for
//    cols 8192..8511 (grid 96, 2 blk/CU, ~12us).
//  - yod_k: fused yoff+ydiag. Same (chunk,head) blocks; y written ONCE
//    (was write + read-modify-write = 128MB extra HBM). accO/accD in regs,
//    LDS = SIt(34.8K)+acs(1K)+union(Ct | xsT+Mt)(34.3K) = 70.1KB -> 2/CU.
//  - out-proj stays on 2ph (grid 512 = 1 round of 2/CU).
// ---------------------------------------------------------------------------

#define B_SZ 2
#define L_SZ 2048
#define H_SZ 2048
#define I_SZ 4096
#define N_SZ 128
#define NH_SZ 64
#define P_SZ 64
#define CH_SZ 256
#define NC_SZ 8
#define PROJ_SZ 8512
#define CONV_SZ 4352
#define XOFF 4096   // xBC start inside proj row
#define DTOFF 8448  // dt start inside proj row
#define BOFF 4096   // B start inside convx row
#define COFF 4224   // C start inside convx row

typedef __attribute__((ext_vector_type(8))) short short8_t;   // 8 bf16 frag
typedef __attribute__((ext_vector_type(4))) float float4_t;   // MFMA acc

// Direct-to-LDS DMA, 16 B per lane, wave-uniform LDS base.
#define GLDS(gp, lp)                                                   \
  __builtin_amdgcn_global_load_lds(                                    \
      (const __attribute__((address_space(1))) void*)(gp),             \
      (__attribute__((address_space(3))) void*)(lp), 16, 0, 0)

__device__ __forceinline__ float bf2f(unsigned short u) {
  union { unsigned int i; float f; } v; v.i = ((unsigned int)u) << 16; return v.f;
}
__device__ __forceinline__ unsigned short f2bf(float f) {
  union { float f; unsigned int i; } v; v.f = f;
  unsigned int b = v.i + 0x7fffu + ((v.i >> 16) & 1u);
  return (unsigned short)(b >> 16);
}
__device__ __forceinline__ void unpack8(uint4 v, float* f) {
  f[0] = bf2f((unsigned short)(v.x & 0xffffu)); f[1] = bf2f((unsigned short)(v.x >> 16));
  f[2] = bf2f((unsigned short)(v.y & 0xffffu)); f[3] = bf2f((unsigned short)(v.y >> 16));
  f[4] = bf2f((unsigned short)(v.z & 0xffffu)); f[5] = bf2f((unsigned short)(v.z >> 16));
  f[6] = bf2f((unsigned short)(v.w & 0xffffu)); f[7] = bf2f((unsigned short)(v.w >> 16));
}
__device__ __forceinline__ float silu_f(float x) { return x / (1.f + expf(-x)); }

__device__ __forceinline__ float load1(const void* p, long long e, int fp32) {
  return fp32 ? ((const float*)p)[e] : bf2f(((const unsigned short*)p)[e]);
}
__device__ __forceinline__ void load4(const void* p, long long e, int fp32, float* f) {
  if (fp32) {
    float4 a = *(const float4*)((const float*)p + e);
    f[0] = a.x; f[1] = a.y; f[2] = a.z; f[3] = a.w;
  } else {
    uint2 v = *(const uint2*)((const unsigned short*)p + e);
    f[0] = bf2f((unsigned short)(v.x & 0xffffu)); f[1] = bf2f((unsigned short)(v.x >> 16));
    f[2] = bf2f((unsigned short)(v.y & 0xffffu)); f[3] = bf2f((unsigned short)(v.y >> 16));
  }
}
__device__ __forceinline__ void load8(const void* p, long long e, int fp32, float* f) {
  if (fp32) {
    float4 a = *(const float4*)((const float*)p + e);
    float4 b = *(const float4*)((const float*)p + e + 4);
    f[0] = a.x; f[1] = a.y; f[2] = a.z; f[3] = a.w;
    f[4] = b.x; f[5] = b.y; f[6] = b.z; f[7] = b.w;
  } else {
    uint4 v = *(const uint4*)((const unsigned short*)p + e);
    unpack8(v, f);
  }
}

// ---------------------------------------------------------------------------
// Per-tensor dtype detector (confirmed working R3/R4).
// ---------------------------------------------------------------------------
__global__ void detect_k(const void* p0, const void* p1, const void* p2,
                         const void* p3, const void* p4, const void* p5,
                         const void* p6, const void* p7, const void* p8,
                         int n0, int n1, int n2, int n3, int n4, int n5,
                         int n6, int n7, int n8, int* flags) {
  __shared__ int pe, po;
  const void* ps[9] = {p0, p1, p2, p3, p4, p5, p6, p7, p8};
  int ns[9] = {n0, n1, n2, n3, n4, n5, n6, n7, n8};
  int t = threadIdx.x;
  for (int i = 0; i < 9; i++) {
    if (t == 0) { pe = 0; po = 0; }
    __syncthreads();
    int S = ns[i] < 256 ? ns[i] : 256;
    if (t < S) {
      unsigned short u = ((const unsigned short*)ps[i])[t];
      int ex = (u >> 7) & 0xFF;
      int plaus = ((u & 0x7FFFu) != 0) && (ex >= 0x70) && (ex <= 0x8F);
      if (plaus) { if (t & 1) atomicAdd(&po, 1); else atomicAdd(&pe, 1); }
    }
    __syncthreads();
    if (t == 0) flags[i] = (2 * pe < po) ? 1 : 0;
    __syncthreads();
  }
  if (t == 0) { flags[14] = 0; flags[15] = 0; }  // internal buffers: bf16
}

// ---------------------------------------------------------------------------
// fp32 (or bf16 passthrough) -> packed bf16. 8 elems/thread. n8 = n/8.
// ---------------------------------------------------------------------------
__global__ __launch_bounds__(256)
void cvt_bf16_k(const void* __restrict__ src, unsigned short* __restrict__ dst,
                long long n8, const int* __restrict__ flags, int fi) {
  long long g = (long long)blockIdx.x * 256 + threadIdx.x;
  if (g >= n8) return;
  long long e = g * 8;
  if (flags[fi]) {
    const float* s = (const float*)src + e;
    float4 a = *(const float4*)s;
    float4 b = *(const float4*)(s + 4);
    unsigned short o[8] = {f2bf(a.x), f2bf(a.y), f2bf(a.z), f2bf(a.w),
                           f2bf(b.x), f2bf(b.y), f2bf(b.z), f2bf(b.w)};
    *(uint4*)(dst + e) = *(const uint4*)o;
  } else {
    *(uint4*)(dst + e) = *(const uint4*)((const unsigned short*)src + e);
  }
}

// ---------------------------------------------------------------------------
// 256x256 8-phase MFMA GEMM (measured 137us on in-proj main).
// Phases paired by kk-slice (8/8/4/4 read profile); 16 MFMA/phase.
// vmcnt(4) once per tile; LDS XOR swizzle via pre-permuted global source.
// Requires M%256==0, K%64==0, grid == (M/256)*gxTiles, nwg%8==0.
// ---------------------------------------------------------------------------
#define MFMA_ACC(d, a, b) \
  d = __builtin_amdgcn_mfma_f32_16x16x32_bf16(a, b, d, 0, 0, 0)
#define LDA_FR(buf, i, kk) \
  (*(const short8_t*)&As[(buf)*16384 + (wm*128 + (i)*16 + l16)*64 + \
                         (((((kk)<<2) + quad) ^ l7) << 3)])
#define LDB_FR(buf, j, kk) \
  (*(const short8_t*)&Bs[(buf)*16384 + (wn*64 + (j)*16 + l16)*64 + \
                         (((((kk)<<2) + quad) ^ l7) << 3)])
#define STAGE_A(h, tile, buf) do {                                          \
    GLDS(aSrc[h][0] + ((long long)(tile) << 6),                             \
         &As[(buf)*16384 + (h)*8192 + (wave*16)*64]);                       \
    GLDS(aSrc[h][1] + ((long long)(tile) << 6),                             \
         &As[(buf)*16384 + (h)*8192 + (wave*16 + 8)*64]);                   \
  } while (0)
#define STAGE_B(h, tile, buf) do {                                          \
    GLDS(bSrc[h][0] + ((long long)(tile) << 6),                             \
         &Bs[(buf)*16384 + (h)*8192 + (wave*16)*64]);                       \
    GLDS(bSrc[h][1] + ((long long)(tile) << 6),                             \
         &Bs[(buf)*16384 + (h)*8192 + (wave*16 + 8)*64]);                   \
  } while (0)

__global__ __launch_bounds__(512, 2)
void gemm_8ph_k(const unsigned short* __restrict__ A,
                const unsigned short* __restrict__ B,
                unsigned short* __restrict__ C,
                int N, int K, int lda, int ldb, int ldc, int gxTiles) {
  __shared__ alignas(16) unsigned short As[2 * 256 * 64];
  __shared__ alignas(16) unsigned short Bs[2 * 256 * 64];
  const int t = threadIdx.x;
  const int lane = t & 63;
  const int wave = t >> 6;
  const int quad = lane >> 4;
  const int l16 = lane & 15;
  const int l7 = lane & 7;
  const int l3 = lane >> 3;
  const int wm = wave >> 2;   // 0..1
  const int wn = wave & 3;    // 0..3

  // T1: banded XCD swizzle.
  int id = blockIdx.x;
  const int nwg = gridDim.x;
  int swz = id;
  if ((nwg & 7) == 0) swz = (id & 7) * (nwg >> 3) + (id >> 3);
  const int band = gxTiles << 2;
  const int by = (swz & 3) + ((swz / band) << 2);
  const int bx = (swz >> 2) % gxTiles;
  const int m0 = by << 8;
  const int n0 = bx << 8;
  const int NT = K >> 6;

  // Per-thread staging source pointers, pre-permuted for the LDS XOR swizzle.
  const int kperm = ((l7 ^ l3) << 3);
  const unsigned short* aSrc[2][2];
  const unsigned short* bSrc[2][2];
#pragma unroll
  for (int h = 0; h < 2; ++h)
#pragma unroll
    for (int c = 0; c < 2; ++c) {
      const int rloc = h * 128 + wave * 16 + c * 8 + l3;
      aSrc[h][c] = A + (long long)(m0 + rloc) * lda + kperm;
      int bn = n0 + rloc;
      if (bn > N - 1) bn = N - 1;  // clamp: edge tiles read a valid row
      bSrc[h][c] = B + (long long)bn * ldb + kperm;
    }

  float4_t acc[8][4];
#pragma unroll
  for (int i = 0; i < 8; ++i)
#pragma unroll
    for (int j = 0; j < 4; ++j) acc[i][j] = (float4_t){0.f, 0.f, 0.f, 0.f};

  // Prologue: tile0 A+B -> buf0 (8 events), tile1 B -> buf1 (4 events).
  STAGE_A(0, 0, 0); STAGE_A(1, 0, 0);
  STAGE_B(0, 0, 0); STAGE_B(1, 0, 0);
  STAGE_B(0, 1, 1); STAGE_B(1, 1, 1);
  asm volatile("s_waitcnt vmcnt(4)" ::: "memory");  // tile0 landed
  __builtin_amdgcn_s_barrier();

  short8_t af[4][2], bf[4][2];
  for (int tt = 0; tt < NT; ++tt) {
    const int rb = tt & 1, nb = rb ^ 1;
    // ---- phase 1: (i0-3 x j0-3) @ kk0 (8 ds_read) ----
#pragma unroll
    for (int i = 0; i < 4; ++i) af[i][0] = LDA_FR(rb, i, 0);
#pragma unroll
    for (int j = 0; j < 4; ++j) bf[j][0] = LDB_FR(rb, j, 0);
    if (tt + 1 < NT) STAGE_A(0, tt + 1, nb);
    asm volatile("s_waitcnt lgkmcnt(4)" ::: "memory");
    __builtin_amdgcn_s_barrier();
    asm volatile("s_waitcnt lgkmcnt(0)" ::: "memory");
    __builtin_amdgcn_s_setprio(1);
#pragma unroll
    for (int i = 0; i < 4; ++i)
#pragma unroll
      for (int j = 0; j < 4; ++j) MFMA_ACC(acc[i][j], af[i][0], bf[j][0]);
    __builtin_amdgcn_s_setprio(0);
    __builtin_amdgcn_s_barrier();
    // ---- phase 2: (i0-3 x j0-3) @ kk1 (8 ds_read) ----
#pragma unroll
    for (int i = 0; i < 4; ++i) af[i][1] = LDA_FR(rb, i, 1);
#pragma unroll
    for (int j = 0; j < 4; ++j) bf[j][1] = LDB_FR(rb, j, 1);
    if (tt + 1 < NT) STAGE_A(1, tt + 1, nb);
    asm volatile("s_waitcnt lgkmcnt(4)" ::: "memory");
    __builtin_amdgcn_s_barrier();
    asm volatile("s_waitcnt lgkmcnt(0)" ::: "memory");
    __builtin_amdgcn_s_setprio(1);
#pragma unroll
    for (int i = 0; i < 4; ++i)
#pragma unroll
      for (int j = 0; j < 4; ++j) MFMA_ACC(acc[i][j], af[i][1], bf[j][1]);
    __builtin_amdgcn_s_setprio(0);
    __builtin_amdgcn_s_barrier();
    // ---- phase 3: (i4-7 x j0-3) @ kk0 (4 ds_read) ----
#pragma unroll
    for (int i = 0; i < 4; ++i) af[i][0] = LDA_FR(rb, 4 + i, 0);
    if (tt + 2 < NT) STAGE_B(0, tt + 2, rb);
    __builtin_amdgcn_s_barrier();
    asm volatile("s_waitcnt lgkmcnt(0)" ::: "memory");
    __builtin_amdgcn_s_setprio(1);
#pragma unroll
    for (int i = 0; i < 4; ++i)
#pragma unroll
      for (int j = 0; j < 4; ++j) MFMA_ACC(acc[4 + i][j], af[i][0], bf[j][0]);
    __builtin_amdgcn_s_setprio(0);
    __builtin_amdgcn_s_barrier();
    // ---- phase 4: (i4-7 x j0-3) @ kk1 (4 ds_read) ----
#pragma unroll
    for (int i = 0; i < 4; ++i) af[i][1] = LDA_FR(rb, 4 + i, 1);
    if (tt + 2 < NT) STAGE_B(1, tt + 2, rb);
    __builtin_amdgcn_s_barrier();
    asm volatile("s_waitcnt lgkmcnt(0)" ::: "memory");
    __builtin_amdgcn_s_setprio(1);
#pragma unroll
    for (int i = 0; i < 4; ++i)
#pragma unroll
      for (int j = 0; j < 4; ++j) MFMA_ACC(acc[4 + i][j], af[i][1], bf[j][1]);
    __builtin_amdgcn_s_setprio(0);
    if (tt < NT - 2) asm volatile("s_waitcnt vmcnt(4)" ::: "memory");
    else             asm volatile("s_waitcnt vmcnt(0)" ::: "memory");
    __builtin_amdgcn_s_barrier();
  }

  // Epilogue: D[m = quad*4+r][n = l16] per 16x16 tile.
#pragma unroll
  for (int i = 0; i < 8; ++i) {
#pragma unroll
    for (int r = 0; r < 4; ++r) {
      const int m = m0 + wm * 128 + i * 16 + quad * 4 + r;
      const long long cb = (long long)m * ldc;
#pragma unroll
      for (int j = 0; j < 4; ++j) {
        const int n = n0 + wn * 64 + j * 16 + l16;
        if (n < N) C[cb + n] = f2bf(acc[i][j][r]);
      }
    }
  }
}

// ---------------------------------------------------------------------------
// 128x128 2-phase MFMA GEMM, 2 blocks/CU (for odd-shaped tiles: in-proj tail,
// out-proj). One barrier per K-tile; t+1 staged at tile top.
// OUT_MODE: 0 bf16 out, 2 runtime (flags[fo] -> fp32).
// Requires M%128==0, K%64==0, grid == (M/128)*gxTiles.
// ---------------------------------------------------------------------------
#define LDA2(buf, i, kk) \
  (*(const short8_t*)&As2[(buf)*8192 + (wm*64 + (i)*16 + l16)*64 + \
                          (((((kk)<<2) + quad) ^ l7) << 3)])
#define LDB2(buf, j, kk) \
  (*(const short8_t*)&Bs2[(buf)*8192 + (wn*64 + (j)*16 + l16)*64 + \
                          (((((kk)<<2) + quad) ^ l7) << 3)])

template <int OUT_MODE>
__global__ __launch_bounds__(256, 2)
void gemm_2ph_k(const unsigned short* __restrict__ A,
                const unsigned short* __restrict__ B,
                void* __restrict__ Cptr,
                int N, int K, int lda, int ldb, int ldc, int gxTiles,
                const int* __restrict__ flags, int fo) {
  __shared__ alignas(16) unsigned short As2[2 * 128 * 64];
  __shared__ alignas(16) unsigned short Bs2[2 * 128 * 64];
  const int t = threadIdx.x;
  const int lane = t & 63;
  const int wave = t >> 6;   // 0..3
  const int quad = lane >> 4;
  const int l16 = lane & 15;
  const int l7 = lane & 7;
  const int l3 = lane >> 3;
  const int wm = wave >> 1;  // 0..1
  const int wn = wave & 1;   // 0..1
  const int ofp = (OUT_MODE == 2) ? flags[fo] : 0;

  // Banded XCD swizzle (bijective for nwg%8==0).
  int id = blockIdx.x;
  const int nwg = gridDim.x;
  int swz = id;
  if ((nwg & 7) == 0) swz = (id & 7) * (nwg >> 3) + (id >> 3);
  const int band = gxTiles << 2;
  const int by = (swz & 3) + ((swz / band) << 2);
  const int bx = (swz >> 2) % gxTiles;
  const int m0 = by << 7;
  const int n0 = bx << 7;
  const int NT = K >> 6;

  const int kperm = ((l7 ^ l3) << 3);
  const unsigned short* aSrc[4];
  const unsigned short* bSrc[4];
#pragma unroll
  for (int c = 0; c < 4; ++c) {
    aSrc[c] = A + (long long)(m0 + wave * 32 + c * 8 + l3) * lda + kperm;
    int bn = n0 + wave * 32 + c * 8 + l3;
    if (bn > N - 1) bn = N - 1;  // edge tiles read a valid row
    bSrc[c] = B + (long long)bn * ldb + kperm;
  }

  float4_t acc[4][4];
#pragma unroll
  for (int i = 0; i < 4; ++i)
#pragma unroll
    for (int j = 0; j < 4; ++j) acc[i][j] = (float4_t){0.f, 0.f, 0.f, 0.f};

#pragma unroll
  for (int c = 0; c < 4; ++c) {
    GLDS(aSrc[c], &As2[(wave * 32 + c * 8) * 64]);
    GLDS(bSrc[c], &Bs2[(wave * 32 + c * 8) * 64]);
  }
  asm volatile("s_waitcnt vmcnt(0)" ::: "memory");
  __builtin_amdgcn_s_barrier();

  short8_t af[4], bfr[4];
  for (int tt = 0; tt < NT; ++tt) {
    const int rb = tt & 1, nb = rb ^ 1;
#pragma unroll
    for (int i = 0; i < 4; ++i) af[i] = LDA2(rb, i, 0);
#pragma unroll
    for (int j = 0; j < 4; ++j) bfr[j] = LDB2(rb, j, 0);
    if (tt + 1 < NT) {
      const long long ko = (long long)(tt + 1) << 6;
#pragma unroll
      for (int c = 0; c < 4; ++c) {
        GLDS(aSrc[c] + ko, &As2[nb * 8192 + (wave * 32 + c * 8) * 64]);
        GLDS(bSrc[c] + ko, &Bs2[nb * 8192 + (wave * 32 + c * 8) * 64]);
      }
    }
    __builtin_amdgcn_s_setprio(1);
#pragma unroll
    for (int i = 0; i < 4; ++i)
#pragma unroll
      for (int j = 0; j < 4; ++j) MFMA_ACC(acc[i][j], af[i], bfr[j]);
    __builtin_amdgcn_s_setprio(0);
#pragma unroll
    for (int i = 0; i < 4; ++i) af[i] = LDA2(rb, i, 1);
#pragma unroll
    for (int j = 0; j < 4; ++j) bfr[j] = LDB2(rb, j, 1);
    __builtin_amdgcn_s_setprio(1);
#pragma unroll
    for (int i = 0; i < 4; ++i)
#pragma unroll
      for (int j = 0; j < 4; ++j) MFMA_ACC(acc[i][j], af[i], bfr[j]);
    __builtin_amdgcn_s_setprio(0);
    asm volatile("s_waitcnt vmcnt(0)" ::: "memory");
    __builtin_amdgcn_s_barrier();
  }

#pragma unroll
  for (int i = 0; i < 4; ++i) {
#pragma unroll
    for (int r = 0; r < 4; ++r) {
      const int m = m0 + wm * 64 + i * 16 + quad * 4 + r;
      const long long cb = (long long)m * ldc;
#pragma unroll
      for (int j = 0; j < 4; ++j) {
        const int n = n0 + wn * 64 + j * 16 + l16;
        if (n < N) {
          float v = acc[i][j][r];
          if (ofp) ((float*)Cptr)[cb + n] = v;
          else     ((unsigned short*)Cptr)[cb + n] = f2bf(v);
        }
      }
    }
  }
}

// ---------------------------------------------------------------------------
// Vector GEMM (small G = Cc@Bc^T batch). fp32 acc. OUT_MODE 1 = fp32 out.
// ---------------------------------------------------------------------------
template <int OUT_MODE>
__global__ __launch_bounds__(256)
void gemm_bt_k(const void* __restrict__ A, const void* __restrict__ B,
               void* __restrict__ Cptr, int M, int N, int K,
               int lda, int ldb, int ldc,
               long long sA, long long sB, long long sC,
               const int* __restrict__ flags, int fa, int fb, int fo) {
  __shared__ float As[128][20];
  __shared__ float Bs[128][20];
  const int t = threadIdx.x;
  const int tx = t & 15, ty = t >> 4;
  const int m0 = blockIdx.y * 128, n0 = blockIdx.x * 128;
  const int afp = flags[fa], bfp = flags[fb];
  const int ofp = (OUT_MODE == 2) ? flags[fo] : (OUT_MODE == 1);
  const long long zoff = (long long)blockIdx.z;
  float* Cf = (float*)Cptr + zoff * sC;
  unsigned short* Cb = (unsigned short*)Cptr + zoff * sC;

  float acc[8][8];
#pragma unroll
  for (int i = 0; i < 8; i++)
#pragma unroll
    for (int j = 0; j < 8; j++) acc[i][j] = 0.f;

  const int rowS = t >> 1;
  const int kof  = (t & 1) * 8;
  const long long aRow = zoff * sA + (long long)(m0 + rowS) * lda + kof;
  const long long bRow = zoff * sB + (long long)(n0 + rowS) * ldb + kof;
  const bool bOK = (n0 + rowS) < N;

  for (int k0 = 0; k0 < K; k0 += 16) {
    float af[8], bf[8];
    load8(A, aRow + k0, afp, af);
    if (bOK) load8(B, bRow + k0, bfp, bf);
    else { bf[0]=bf[1]=bf[2]=bf[3]=bf[4]=bf[5]=bf[6]=bf[7]=0.f; }
    __syncthreads();
    *(float4*)&As[rowS][kof]     = make_float4(af[0], af[1], af[2], af[3]);
    *(float4*)&As[rowS][kof + 4] = make_float4(af[4], af[5], af[6], af[7]);
    *(float4*)&Bs[rowS][kof]     = make_float4(bf[0], bf[1], bf[2], bf[3]);
    *(float4*)&Bs[rowS][kof + 4] = make_float4(bf[4], bf[5], bf[6], bf[7]);
    __syncthreads();
#pragma unroll
    for (int kk = 0; kk < 16; kk += 2) {
      float2 a2[8], b2[8];
#pragma unroll
      for (int i = 0; i < 8; i++) a2[i] = *(const float2*)&As[ty + 16 * i][kk];
#pragma unroll
      for (int j = 0; j < 8; j++) b2[j] = *(const float2*)&Bs[tx + 16 * j][kk];
#pragma unroll
      for (int i = 0; i < 8; i++)
#pragma unroll
        for (int j = 0; j < 8; j++) {
          acc[i][j] = fmaf(a2[i].x, b2[j].x, acc[i][j]);
          acc[i][j] = fmaf(a2[i].y, b2[j].y, acc[i][j]);
        }
    }
  }
#pragma unroll
  for (int i = 0; i < 8; i++) {
    const int m = m0 + ty + 16 * i;
    const long long base = (long long)m * ldc;
#pragma unroll
    for (int j = 0; j < 8; j++) {
      const int n = n0 + tx + 16 * j;
      if (n < N) {
        if (ofp) Cf[base + n] = acc[i][j];
        else     Cb[base + n] = f2bf(acc[i][j]);
      }
    }
  }
}

// ---------------------------------------------------------------------------
// Depthwise causal conv (K=4) + bias + SiLU over xBC columns of proj.
// ---------------------------------------------------------------------------
__global__ __launch_bounds__(256)
void conv_silu_k(const unsigned short* __restrict__ proj,
                 const void* __restrict__ cw,
                 const void* __restrict__ cb,
                 unsigned short* __restrict__ convx,
                 const int* __restrict__ flags) {
  const int total = B_SZ * L_SZ * (CONV_SZ / 4);
  int g = blockIdx.x * 256 + threadIdx.x;
  if (g >= total) return;
  const int fw = flags[2], fb = flags[3];
  int c4 = g % (CONV_SZ / 4);
  int bl = g / (CONV_SZ / 4);
  int l = bl & (L_SZ - 1);
  int ch = c4 * 4;
  float w0[8], w1[8];
  load8(cw, (long long)ch * 4, fw, w0);
  load8(cw, (long long)ch * 4 + 8, fw, w1);
  float accv[4];
  load4(cb, ch, fb, accv);
  float acc0 = accv[0], acc1 = accv[1], acc2 = accv[2], acc3 = accv[3];
  const long long rb = (long long)(bl - l);
#pragma unroll
  for (int k = 0; k < 4; k++) {
    int ls = l - 3 + k;
    if (ls < 0) continue;
    uint2 xv = *(const uint2*)(proj + (rb + ls) * PROJ_SZ + XOFF + ch);
    float x0 = bf2f((unsigned short)(xv.x & 0xffffu));
    float x1 = bf2f((unsigned short)(xv.x >> 16));
    float x2 = bf2f((unsigned short)(xv.y & 0xffffu));
    float x3 = bf2f((unsigned short)(xv.y >> 16));
    acc0 = fmaf(x0, w0[k], acc0);
    acc1 = fmaf(x1, w0[4 + k], acc1);
    acc2 = fmaf(x2, w1[k], acc2);
    acc3 = fmaf(x3, w1[4 + k], acc3);
  }
  unsigned short o0 = f2bf(silu_f(acc0));
  unsigned short o1 = f2bf(silu_f(acc1));
  unsigned short o2 = f2bf(silu_f(acc2));
  unsigned short o3 = f2bf(silu_f(acc3));
  *(uint2*)(convx + (long long)bl * CONV_SZ + ch) =
      make_uint2((unsigned int)o0 | ((unsigned int)o1 << 16),
                 (unsigned int)o2 | ((unsigned int)o3 << 16));
}

// ---------------------------------------------------------------------------
__global__ __launch_bounds__(256)
void dt_prep_k(const unsigned short* __restrict__ proj,
               const void* __restrict__ dt_bias,
               float* __restrict__ dtv, const int* __restrict__ flags) {
  int g = blockIdx.x * 256 + threadIdx.x;
  int h = g & 63;
  long long bl = g >> 6;
  float v = bf2f(proj[bl * PROJ_SZ + DTOFF + h]) + load1(dt_bias, h, flags[4]);
  float sp = (v > 20.f) ? v : log1pf(expf(v));
  dtv[g] = sp;
}

// ---------------------------------------------------------------------------
__global__ __launch_bounds__(256)
void acs_scan_k(const float* __restrict__ dtv,
                const void* __restrict__ A_log,
                float* __restrict__ acs, const int* __restrict__ flags) {
  __shared__ float sd[256];
  int blk = blockIdx.x;
  int h = blk & 63;
  int bc = blk >> 6;
  int l = threadIdx.x;
  float Ah = -expf(load1(A_log, h, flags[5]));
  long long row = (long long)bc * CH_SZ + l;
  sd[l] = Ah * dtv[row * NH_SZ + h];
  for (int off = 1; off < 256; off <<= 1) {
    __syncthreads();
    float tv = (l >= off) ? sd[l - off] : 0.f;
    __syncthreads();
    sd[l] += tv;
  }
  acs[(long long)blk * CH_SZ + l] = sd[l];
}

// ---------------------------------------------------------------------------
__global__ __launch_bounds__(256)
void chunk_states_k(const unsigned short* __restrict__ convx,
                    const float* __restrict__ dtv,
                    const float* __restrict__ acs,
                    float* __restrict__ stc) {
  __shared__ float Bw[32][128];
  __shared__ float xw[32][64];
  int blk = blockIdx.x;
  int h = blk & 63;
  int bc = blk >> 6;
  int t = threadIdx.x;
  const int p0 = (t & 15) * 4, n0 = (t >> 4) * 8;
  const float* acsb = acs + (long long)blk * 256;
  const float alast = acsb[255];
  float acc[4][8];
#pragma unroll
  for (int i = 0; i < 4; i++)
#pragma unroll
    for (int j = 0; j < 8; j++) acc[i][j] = 0.f;
  const long long row0 = (long long)bc * 256;

  for (int lt0 = 0; lt0 < 256; lt0 += 32) {
    __syncthreads();
#pragma unroll
    for (int q = 0; q < 4; q++) {
      int idx4 = (t + 256 * q) * 4;
      int r = idx4 >> 7, n = idx4 & 127;
      uint2 v = *(const uint2*)(convx + (row0 + lt0 + r) * CONV_SZ + BOFF + n);
      Bw[r][n]     = bf2f((unsigned short)(v.x & 0xffffu));
      Bw[r][n + 1] = bf2f((unsigned short)(v.x >> 16));
      Bw[r][n + 2] = bf2f((unsigned short)(v.y & 0xffffu));
      Bw[r][n + 3] = bf2f((unsigned short)(v.y >> 16));
    }
#pragma unroll
    for (int q = 0; q < 2; q++) {
      int idx4 = (t + 256 * q) * 4;
      int r = idx4 >> 6, p = idx4 & 63;
      long long lg = row0 + lt0 + r;
      float sc = dtv[lg * NH_SZ + h] * expf(alast - acsb[lt0 + r]);
      uint2 v = *(const uint2*)(convx + lg * CONV_SZ + h * 64 + p);
      xw[r][p]     = bf2f((unsigned short)(v.x & 0xffffu)) * sc;
      xw[r][p + 1] = bf2f((unsigned short)(v.x >> 16)) * sc;
      xw[r][p + 2] = bf2f((unsigned short)(v.y & 0xffffu)) * sc;
      xw[r][p + 3] = bf2f((unsigned short)(v.y >> 16)) * sc;
    }
    __syncthreads();
#pragma unroll 4
    for (int lt = 0; lt < 32; lt++) {
      float4 xv = *(const float4*)&xw[lt][p0];
      float4 b0 = *(const float4*)&Bw[lt][n0];
      float4 b1 = *(const float4*)&Bw[lt][n0 + 4];
      float xa[4] = {xv.x, xv.y, xv.z, xv.w};
      float ba[8] = {b0.x, b0.y, b0.z, b0.w, b1.x, b1.y, b1.z, b1.w};
#pragma unroll
      for (int i = 0; i < 4; i++)
#pragma unroll
        for (int j = 0; j < 8; j++) acc[i][j] = fmaf(xa[i], ba[j], acc[i][j]);
    }
  }
  float* outb = stc + (long long)blk * 8192;
#pragma unroll
  for (int i = 0; i < 4; i++) {
    *(float4*)&outb[(p0 + i) * 128 + n0] =
        make_float4(acc[i][0], acc[i][1], acc[i][2], acc[i][3]);
    *(float4*)&outb[(p0 + i) * 128 + n0 + 4] =
        make_float4(acc[i][4], acc[i][5], acc[i][6], acc[i][7]);
  }
}

// ---------------------------------------------------------------------------
__global__ __launch_bounds__(256)
void recur_k(float* __restrict__ stc, const float* __restrict__ acs) {
  int blk = blockIdx.x;
  int b = blk >> 6, h = blk & 63;
  int t = threadIdx.x;
  float S[32];
#pragma unroll
  for (int j = 0; j < 32; j++) S[j] = 0.f;
  for (int z = 0; z < 8; z++) {
    long long bz = ((long long)b * 8 + z) * 64 + h;
    long long base = bz * 8192;
    float e = expf(acs[bz * 256 + 255]);
#pragma unroll
    for (int j = 0; j < 32; j++) {
      int idx = j * 256 + t;
      float cs = stc[base + idx];
      stc[base + idx] = S[j];
      S[j] = fmaf(e, S[j], cs);
    }
  }
}

// ---------------------------------------------------------------------------
// Fused Y_off + Y_diag + D*x  ->  y written ONCE (was: yoff wrote y, ydiag
// did a 128MB read-modify-write pass). Same math, fp32 throughout.
// LDS: SIt 34.8K + acs_s 1K + union(Ct 16K | xsT 17.4K + Mt 16.9K) 34.3K
//    = 70.1KB -> 2 blocks/CU.
// ---------------------------------------------------------------------------
__global__ __launch_bounds__(256)
void yod_k(const unsigned short* __restrict__ convx,
           const float* __restrict__ sti,
           const float* __restrict__ acs,
           const float* __restrict__ dtv,
           const float* __restrict__ Gmat,
           const void* __restrict__ Dw,
           float* __restrict__ y, const int* __restrict__ flags) {
  __shared__ float SIt[128][68];
  __shared__ float acs_s[256];
  __shared__ alignas(16) float ubuf[64 * 68 + 64 * 66];  // xsT | Mt ; Ct aliases
  float (*xsT)[68] = (float (*)[68])ubuf;
  float (*Mt)[66]  = (float (*)[66])(ubuf + 64 * 68);
  unsigned short (*Ct)[128] = (unsigned short (*)[128])ubuf;

  int blk = blockIdx.x;
  int h = blk & 63;
  int bc = blk >> 6;
  int t = threadIdx.x;
  const int txp = t & 15, lq = t >> 4;
  const float Dh = load1(Dw, h, flags[6]);
  const float* sib = sti + (long long)blk * 8192;
#pragma unroll 4
  for (int q = 0; q < 32; q++) {
    int idx = t + 256 * q;
    SIt[idx & 127][idx >> 7] = sib[idx];
  }
  acs_s[t] = acs[(long long)blk * 256 + t];
  const long long row0 = (long long)bc * 256;
  const float* Gb = Gmat + (long long)bc * 65536;

  for (int ltile = 0; ltile < 4; ltile++) {
    __syncthreads();  // SIt/acs_s ready (iter 0); prior xsT/Mt reads done
    // ---- phase A: C tile -> Ct, accO = C @ SI^T ----
#pragma unroll 4
    for (int q = 0; q < 32; q++) {
      int idx = t + 256 * q;
      int lr = idx >> 7, n = idx & 127;
      Ct[lr][n] = convx[(row0 + ltile * 64 + lr) * CONV_SZ + COFF + n];
    }
    __syncthreads();
    float accO[4][4] = {};
#pragma unroll 4
    for (int n = 0; n < 128; n++) {
      float4 sv = *(const float4*)&SIt[n][txp * 4];
      float c0 = bf2f(Ct[lq * 4 + 0][n]);
      float c1 = bf2f(Ct[lq * 4 + 1][n]);
      float c2 = bf2f(Ct[lq * 4 + 2][n]);
      float c3 = bf2f(Ct[lq * 4 + 3][n]);
      accO[0][0] = fmaf(c0, sv.x, accO[0][0]); accO[0][1] = fmaf(c0, sv.y, accO[0][1]);
      accO[0][2] = fmaf(c0, sv.z, accO[0][2]); accO[0][3] = fmaf(c0, sv.w, accO[0][3]);
      accO[1][0] = fmaf(c1, sv.x, accO[1][0]); accO[1][1] = fmaf(c1, sv.y, accO[1][1]);
      accO[1][2] = fmaf(c1, sv.z, accO[1][2]); accO[1][3] = fmaf(c1, sv.w, accO[1][3]);
      accO[2][0] = fmaf(c2, sv.x, accO[2][0]); accO[2][1] = fmaf(c2, sv.y, accO[2][1]);
      accO[2][2] = fmaf(c2, sv.z, accO[2][2]); accO[2][3] = fmaf(c2, sv.w, accO[2][3]);
      accO[3][0] = fmaf(c3, sv.x, accO[3][0]); accO[3][1] = fmaf(c3, sv.y, accO[3][1]);
      accO[3][2] = fmaf(c3, sv.z, accO[3][2]); accO[3][3] = fmaf(c3, sv.w, accO[3][3]);
    }
    // ---- phase B: triangular Y_diag over stiles ----
    float accD[4][4] = {};
    for (int stile = 0; stile <= ltile; stile++) {
      __syncthreads();  // Ct reads (stile 0) / prior xsT,Mt reads done
#pragma unroll 4
      for (int q = 0; q < 16; q++) {
        int idx = t + 256 * q;
        int ss = idx >> 6, p = idx & 63;
        long long row = row0 + stile * 64 + ss;
        xsT[ss][p] = bf2f(convx[row * CONV_SZ + h * 64 + p]) * dtv[row * NH_SZ + h];
      }
#pragma unroll 4
      for (int q = 0; q < 16; q++) {
        int idx = t + 256 * q;
        int lr = idx >> 6, ss = idx & 63;
        int lg = ltile * 64 + lr, sg = stile * 64 + ss;
        float m = 0.f;
        if (sg <= lg) m = Gb[(long long)lg * 256 + sg] * expf(acs_s[lg] - acs_s[sg]);
        Mt[lr][ss] = m;
      }
      __syncthreads();
#pragma unroll 4
      for (int ss = 0; ss < 64; ss++) {
        float4 xv = *(const float4*)&xsT[ss][txp * 4];
        float m0 = Mt[lq * 4 + 0][ss];
        float m1 = Mt[lq * 4 + 1][ss];
        float m2 = Mt[lq * 4 + 2][ss];
        float m3 = Mt[lq * 4 + 3][ss];
        accD[0][0] = fmaf(m0, xv.x, accD[0][0]); accD[0][1] = fmaf(m0, xv.y, accD[0][1]);
        accD[0][2] = fmaf(m0, xv.z, accD[0][2]); accD[0][3] = fmaf(m0, xv.w, accD[0][3]);
        accD[1][0] = fmaf(m1, xv.x, accD[1][0]); accD[1][1] = fmaf(m1, xv.y, accD[1][1]);
        accD[1][2] = fmaf(m1, xv.z, accD[1][2]); accD[1][3] = fmaf(m1, xv.w, accD[1][3]);
        accD[2][0] = fmaf(m2, xv.x, accD[2][0]); accD[2][1] = fmaf(m2, xv.y, accD[2][1]);
        accD[2][2] = fmaf(m2, xv.z, accD[2][2]); accD[2][3] = fmaf(m2, xv.w, accD[2][3]);
        accD[3][0] = fmaf(m3, xv.x, accD[3][0]); accD[3][1] = fmaf(m3, xv.y, accD[3][1]);
        accD[3][2] = fmaf(m3, xv.z, accD[3][2]); accD[3][3] = fmaf(m3, xv.w, accD[3][3]);
      }
    }
    // ---- write: y = exp(acs)*accO + D*x + accD ----
#pragma unroll
    for (int i = 0; i < 4; i++) {
      int lloc = ltile * 64 + lq * 4 + i;
      long long row = row0 + lloc;
      float ex = expf(acs_s[lloc]);
      uint2 xv = *(const uint2*)(convx + row * CONV_SZ + h * 64 + txp * 4);
      float4 o;
      o.x = fmaf(ex, accO[i][0], Dh * bf2f((unsigned short)(xv.x & 0xffffu))) + accD[i][0];
      o.y = fmaf(ex, accO[i][1], Dh * bf2f((unsigned short)(xv.x >> 16)))     + accD[i][1];
      o.z = fmaf(ex, accO[i][2], Dh * bf2f((unsigned short)(xv.y & 0xffffu))) + accD[i][2];
      o.w = fmaf(ex, accO[i][3], Dh * bf2f((unsigned short)(xv.y >> 16)))     + accD[i][3];
      *(float4*)&y[row * I_SZ + h * 64 + txp * 4] = o;
    }
  }
}

// ---------------------------------------------------------------------------
__global__ __launch_bounds__(256)
void norm_k(const float* __restrict__ y,
            const unsigned short* __restrict__ proj,
            const void* __restrict__ nw,
            unsigned short* __restrict__ yfb, const int* __restrict__ flags) {
  __shared__ float red[4];
  __shared__ float sc_s;
  int row = blockIdx.x;
  int t = threadIdx.x;
  const int fn = flags[7];
  const float* yr = y + (long long)row * I_SZ;
  const unsigned short* zr = proj + (long long)row * PROJ_SZ;
  float g[16];
  float ss = 0.f;
#pragma unroll
  for (int q = 0; q < 4; q++) {
    int i0 = q * 1024 + t * 4;
    float4 yv = *(const float4*)&yr[i0];
    uint2 zv = *(const uint2*)&zr[i0];
    float z0 = bf2f((unsigned short)(zv.x & 0xffffu));
    float z1 = bf2f((unsigned short)(zv.x >> 16));
    float z2 = bf2f((unsigned short)(zv.y & 0xffffu));
    float z3 = bf2f((unsigned short)(zv.y >> 16));
    float g0 = yv.x * silu_f(z0), g1 = yv.y * silu_f(z1);
    float g2 = yv.z * silu_f(z2), g3 = yv.w * silu_f(z3);
    g[q * 4 + 0] = g0; g[q * 4 + 1] = g1; g[q * 4 + 2] = g2; g[q * 4 + 3] = g3;
    ss += g0 * g0 + g1 * g1 + g2 * g2 + g3 * g3;
  }
#pragma unroll
  for (int off = 32; off > 0; off >>= 1) ss += __shfl_down(ss, off, 64);
  if ((t & 63) == 0) red[t >> 6] = ss;
  __syncthreads();
  if (t == 0) sc_s = rsqrtf((red[0] + red[1] + red[2] + red[3]) * (1.f / 4096.f) + 1e-5f);
  __syncthreads();
  float sc = sc_s;
#pragma unroll
  for (int q = 0; q < 4; q++) {
    int i0 = q * 1024 + t * 4;
    float nv[4];
    load4(nw, i0, fn, nv);
    unsigned short o0 = f2bf(g[q * 4 + 0] * sc * nv[0]);
    unsigned short o1 = f2bf(g[q * 4 + 1] * sc * nv[1]);
    unsigned short o2 = f2bf(g[q * 4 + 2] * sc * nv[2]);
    unsigned short o3 = f2bf(g[q * 4 + 3] * sc * nv[3]);
    *(uint2*)&yfb[(long long)row * I_SZ + i0] =
        make_uint2((unsigned int)o0 | ((unsigned int)o1 << 16),
                   (unsigned int)o2 | ((unsigned int)o3 << 16));
  }
}

// ---------------------------------------------------------------------------
extern "C" void kernel_launch(void* const* d_in, const int* in_sizes, int n_in,
                              void* d_out, int out_size, void* d_ws, size_t ws_size,
                              hipStream_t stream) {
  const void* hs     = d_in[0];
  const void* W_in   = d_in[1];
  const void* conv_w = d_in[2];
  const void* conv_b = d_in[3];
  const void* dt_b   = d_in[4];
  const void* A_log  = d_in[5];
  const void* Dw     = d_in[6];
  const void* nw     = d_in[7];
  const void* W_out  = d_in[8];

  char* ws = (char*)d_ws;
  size_t off = 0;
  auto alloc = [&](size_t bytes) -> void* {
    void* p = ws + off;
    off += (bytes + 255) & ~(size_t)255;
    return p;
  };
  const long long ML = (long long)B_SZ * L_SZ;  // 4096 rows
  int* flags = (int*)alloc(64);
  unsigned short* proj  = (unsigned short*)alloc(ML * PROJ_SZ * 2);             // 66.5 MB
  unsigned short* convx = (unsigned short*)alloc(ML * CONV_SZ * 2);             // 34 MB
  float* dtv  = (float*)alloc(ML * NH_SZ * 4);                                  // 1 MB
  float* acsb = (float*)alloc((long long)B_SZ * NC_SZ * NH_SZ * CH_SZ * 4);     // 1 MB
  float* Gm   = (float*)alloc((long long)B_SZ * NC_SZ * CH_SZ * CH_SZ * 4);     // 4 MB
  float* stc  = (float*)alloc((long long)B_SZ * NC_SZ * NH_SZ * P_SZ * N_SZ * 4);  // 32 MB
  float* yb   = (float*)alloc(ML * I_SZ * 4);                                   // 64 MB
  unsigned short* yfb = (unsigned short*)stc;  // alias: stc dead after yod_k
  // bf16 staging copies alias the yb region (dead until yod_k / after norm_k)
  unsigned short* hs_bf   = (unsigned short*)yb;                 // 16 MB
  unsigned short* Win_bf  = (unsigned short*)yb + 8388608;       // 34.9 MB (ends <51MB)
  unsigned short* Wout_bf = (unsigned short*)yb;                 // 16 MB (after norm_k)
  (void)n_in; (void)out_size;
  if (off > ws_size) return;

  dim3 blk(256);
  // 0. per-tensor dtype detection
  detect_k<<<1, blk, 0, stream>>>(hs, W_in, conv_w, conv_b, dt_b, A_log, Dw, nw, W_out,
                                  in_sizes[0], in_sizes[1], in_sizes[2], in_sizes[3],
                                  in_sizes[4], in_sizes[5], in_sizes[6], in_sizes[7],
                                  in_sizes[8], flags);
  // 0a. convert hs, W_in to packed bf16
  cvt_bf16_k<<<dim3(4096), blk, 0, stream>>>(hs, hs_bf, 1048576LL, flags, 0);
  cvt_bf16_k<<<dim3(8512), blk, 0, stream>>>(W_in, Win_bf, 2179072LL, flags, 1);
  // 1. in-proj: proj[4096,8512] = hs @ W_in^T  (bf16 out)
  //    cols 0..8191 via 256^2 8-phase (512 blocks = exactly 2 rounds @ 1/CU)
  gemm_8ph_k<<<dim3(512), dim3(512), 0, stream>>>(
      hs_bf, Win_bf, proj, PROJ_SZ, H_SZ, H_SZ, H_SZ, PROJ_SZ, /*gxTiles=*/32);
  //    cols 8192..8511 (320 cols) via 2ph (grid 32x3 = 96 blocks, 2/CU)
  gemm_2ph_k<0><<<dim3(96), blk, 0, stream>>>(
      hs_bf, Win_bf + 8192LL * 2048, proj + 8192, 320, H_SZ,
      H_SZ, H_SZ, PROJ_SZ, /*gxTiles=*/3, flags, 15);
  // 2. conv + silu
  conv_silu_k<<<dim3((B_SZ * L_SZ * (CONV_SZ / 4) + 255) / 256), blk, 0, stream>>>(
      proj, conv_w, conv_b, convx, flags);
  // 3. dt
  dt_prep_k<<<dim3((unsigned)(ML * NH_SZ / 256)), blk, 0, stream>>>(proj, dt_b, dtv, flags);
  // 4. cumsum A*dt
  acs_scan_k<<<dim3(B_SZ * NC_SZ * NH_SZ), blk, 0, stream>>>(dtv, A_log, acsb, flags);
  // 5. G = Cc @ Bc^T per (b,chunk)  (fp32 out, vector path)
  gemm_bt_k<1><<<dim3(2, 2, 16), blk, 0, stream>>>(
      (const unsigned short*)convx + COFF, (const unsigned short*)convx + BOFF,
      Gm, 256, 256, 128, CONV_SZ, CONV_SZ, 256,
      (long long)256 * CONV_SZ, (long long)256 * CONV_SZ, 65536,
      flags, 15, 15, 15);
  // 6. per-chunk states
  chunk_states_k<<<dim3(1024), blk, 0, stream>>>(convx, dtv, acsb, stc);
  // 7. inter-chunk recurrence (in-place on stc)
  recur_k<<<dim3(B_SZ * NH_SZ), blk, 0, stream>>>(stc, acsb);
  // 8. fused Y_off + Y_diag + D*x  (single y write; overwrites yb)
  yod_k<<<dim3(1024), blk, 0, stream>>>(convx, stc, acsb, dtv, Gm, Dw, yb, flags);
  // 9. gated RMSNorm
  norm_k<<<dim3((unsigned)ML), blk, 0, stream>>>(yb, proj, nw, yfb, flags);
  // 9a. convert W_out (yb now dead)
  cvt_bf16_k<<<dim3(4096), blk, 0, stream>>>(W_out, Wout_bf, 1048576LL, flags, 8);
  // 10. out-proj: out = yf @ W_out^T, grid 32x16 = 512 blocks = 1 round of
  //     2 blocks/CU. Output dtype follows hs flag.
  gemm_2ph_k<2><<<dim3(512), blk, 0, stream>>>(
      yfb, Wout_bf, d_out, H_SZ, I_SZ, I_SZ, I_SZ, H_SZ, /*gxTiles=*/16,
      flags, 0);
}

// Round 6
// 726.856 us; speedup vs baseline: 1.1003x; 1.1003x over previous
//
#include <hip/hip_runtime.h>
#include <hip/hip_bf16.h>
#include <math.h>

// ---------------------------------------------------------------------------
// Mamba2 mixer forward, MI355X. Round 12: revert yod fusion (occupancy loss).
// R11: 800us. yod_k (70KB LDS -> 2 blk/CU) = 272us vs separate pair ~205us:
// fusion dropped occupancy on latency-bound VALU kernels; y RMW traffic was
// L2/L3-absorbed (FETCH 54MB) so the "saved" 128MB never cost HBM. Revert to
// R9's yoff_k + ydiag_k; keep R10's in-proj split (8ph 137us + 2ph tail) and
// 2ph out-proj. All components individually measured-good.
// ---------------------------------------------------------------------------

#define B_SZ 2
#define L_SZ 2048
#define H_SZ 2048
#define I_SZ 4096
#define N_SZ 128
#define NH_SZ 64
#define P_SZ 64
#define CH_SZ 256
#define NC_SZ 8
#define PROJ_SZ 8512
#define CONV_SZ 4352
#define XOFF 4096   // xBC start inside proj row
#define DTOFF 8448  // dt start inside proj row
#define BOFF 4096   // B start inside convx row
#define COFF 4224   // C start inside convx row

typedef __attribute__((ext_vector_type(8))) short short8_t;   // 8 bf16 frag
typedef __attribute__((ext_vector_type(4))) float float4_t;   // MFMA acc

// Direct-to-LDS DMA, 16 B per lane, wave-uniform LDS base.
#define GLDS(gp, lp)                                                   \
  __builtin_amdgcn_global_load_lds(                                    \
      (const __attribute__((address_space(1))) void*)(gp),             \
      (__attribute__((address_space(3))) void*)(lp), 16, 0, 0)

__device__ __forceinline__ float bf2f(unsigned short u) {
  union { unsigned int i; float f; } v; v.i = ((unsigned int)u) << 16; return v.f;
}
__device__ __forceinline__ unsigned short f2bf(float f) {
  union { float f; unsigned int i; } v; v.f = f;
  unsigned int b = v.i + 0x7fffu + ((v.i >> 16) & 1u);
  return (unsigned short)(b >> 16);
}
__device__ __forceinline__ void unpack8(uint4 v, float* f) {
  f[0] = bf2f((unsigned short)(v.x & 0xffffu)); f[1] = bf2f((unsigned short)(v.x >> 16));
  f[2] = bf2f((unsigned short)(v.y & 0xffffu)); f[3] = bf2f((unsigned short)(v.y >> 16));
  f[4] = bf2f((unsigned short)(v.z & 0xffffu)); f[5] = bf2f((unsigned short)(v.z >> 16));
  f[6] = bf2f((unsigned short)(v.w & 0xffffu)); f[7] = bf2f((unsigned short)(v.w >> 16));
}
__device__ __forceinline__ float silu_f(float x) { return x / (1.f + expf(-x)); }

__device__ __forceinline__ float load1(const void* p, long long e, int fp32) {
  return fp32 ? ((const float*)p)[e] : bf2f(((const unsigned short*)p)[e]);
}
__device__ __forceinline__ void load4(const void* p, long long e, int fp32, float* f) {
  if (fp32) {
    float4 a = *(const float4*)((const float*)p + e);
    f[0] = a.x; f[1] = a.y; f[2] = a.z; f[3] = a.w;
  } else {
    uint2 v = *(const uint2*)((const unsigned short*)p + e);
    f[0] = bf2f((unsigned short)(v.x & 0xffffu)); f[1] = bf2f((unsigned short)(v.x >> 16));
    f[2] = bf2f((unsigned short)(v.y & 0xffffu)); f[3] = bf2f((unsigned short)(v.y >> 16));
  }
}
__device__ __forceinline__ void load8(const void* p, long long e, int fp32, float* f) {
  if (fp32) {
    float4 a = *(const float4*)((const float*)p + e);
    float4 b = *(const float4*)((const float*)p + e + 4);
    f[0] = a.x; f[1] = a.y; f[2] = a.z; f[3] = a.w;
    f[4] = b.x; f[5] = b.y; f[6] = b.z; f[7] = b.w;
  } else {
    uint4 v = *(const uint4*)((const unsigned short*)p + e);
    unpack8(v, f);
  }
}

// ---------------------------------------------------------------------------
// Per-tensor dtype detector (confirmed working R3/R4).
// ---------------------------------------------------------------------------
__global__ void detect_k(const void* p0, const void* p1, const void* p2,
                         const void* p3, const void* p4, const void* p5,
                         const void* p6, const void* p7, const void* p8,
                         int n0, int n1, int n2, int n3, int n4, int n5,
                         int n6, int n7, int n8, int* flags) {
  __shared__ int pe, po;
  const void* ps[9] = {p0, p1, p2, p3, p4, p5, p6, p7, p8};
  int ns[9] = {n0, n1, n2, n3, n4, n5, n6, n7, n8};
  int t = threadIdx.x;
  for (int i = 0; i < 9; i++) {
    if (t == 0) { pe = 0; po = 0; }
    __syncthreads();
    int S = ns[i] < 256 ? ns[i] : 256;
    if (t < S) {
      unsigned short u = ((const unsigned short*)ps[i])[t];
      int ex = (u >> 7) & 0xFF;
      int plaus = ((u & 0x7FFFu) != 0) && (ex >= 0x70) && (ex <= 0x8F);
      if (plaus) { if (t & 1) atomicAdd(&po, 1); else atomicAdd(&pe, 1); }
    }
    __syncthreads();
    if (t == 0) flags[i] = (2 * pe < po) ? 1 : 0;
    __syncthreads();
  }
  if (t == 0) { flags[14] = 0; flags[15] = 0; }  // internal buffers: bf16
}

// ---------------------------------------------------------------------------
// fp32 (or bf16 passthrough) -> packed bf16. 8 elems/thread. n8 = n/8.
// ---------------------------------------------------------------------------
__global__ __launch_bounds__(256)
void cvt_bf16_k(const void* __restrict__ src, unsigned short* __restrict__ dst,
                long long n8, const int* __restrict__ flags, int fi) {
  long long g = (long long)blockIdx.x * 256 + threadIdx.x;
  if (g >= n8) return;
  long long e = g * 8;
  if (flags[fi]) {
    const float* s = (const float*)src + e;
    float4 a = *(const float4*)s;
    float4 b = *(const float4*)(s + 4);
    unsigned short o[8] = {f2bf(a.x), f2bf(a.y), f2bf(a.z), f2bf(a.w),
                           f2bf(b.x), f2bf(b.y), f2bf(b.z), f2bf(b.w)};
    *(uint4*)(dst + e) = *(const uint4*)o;
  } else {
    *(uint4*)(dst + e) = *(const uint4*)((const unsigned short*)src + e);
  }
}

// ---------------------------------------------------------------------------
// 256x256 8-phase MFMA GEMM (measured 137us on in-proj main).
// Phases paired by kk-slice (8/8/4/4 read profile); 16 MFMA/phase.
// vmcnt(4) once per tile; LDS XOR swizzle via pre-permuted global source.
// Requires M%256==0, K%64==0, grid == (M/256)*gxTiles, nwg%8==0.
// ---------------------------------------------------------------------------
#define MFMA_ACC(d, a, b) \
  d = __builtin_amdgcn_mfma_f32_16x16x32_bf16(a, b, d, 0, 0, 0)
#define LDA_FR(buf, i, kk) \
  (*(const short8_t*)&As[(buf)*16384 + (wm*128 + (i)*16 + l16)*64 + \
                         (((((kk)<<2) + quad) ^ l7) << 3)])
#define LDB_FR(buf, j, kk) \
  (*(const short8_t*)&Bs[(buf)*16384 + (wn*64 + (j)*16 + l16)*64 + \
                         (((((kk)<<2) + quad) ^ l7) << 3)])
#define STAGE_A(h, tile, buf) do {                                          \
    GLDS(aSrc[h][0] + ((long long)(tile) << 6),                             \
         &As[(buf)*16384 + (h)*8192 + (wave*16)*64]);                       \
    GLDS(aSrc[h][1] + ((long long)(tile) << 6),                             \
         &As[(buf)*16384 + (h)*8192 + (wave*16 + 8)*64]);                   \
  } while (0)
#define STAGE_B(h, tile, buf) do {                                          \
    GLDS(bSrc[h][0] + ((long long)(tile) << 6),                             \
         &Bs[(buf)*16384 + (h)*8192 + (wave*16)*64]);                       \
    GLDS(bSrc[h][1] + ((long long)(tile) << 6),                             \
         &Bs[(buf)*16384 + (h)*8192 + (wave*16 + 8)*64]);                   \
  } while (0)

__global__ __launch_bounds__(512, 2)
void gemm_8ph_k(const unsigned short* __restrict__ A,
                const unsigned short* __restrict__ B,
                unsigned short* __restrict__ C,
                int N, int K, int lda, int ldb, int ldc, int gxTiles) {
  __shared__ alignas(16) unsigned short As[2 * 256 * 64];
  __shared__ alignas(16) unsigned short Bs[2 * 256 * 64];
  const int t = threadIdx.x;
  const int lane = t & 63;
  const int wave = t >> 6;
  const int quad = lane >> 4;
  const int l16 = lane & 15;
  const int l7 = lane & 7;
  const int l3 = lane >> 3;
  const int wm = wave >> 2;   // 0..1
  const int wn = wave & 3;    // 0..3

  // T1: banded XCD swizzle.
  int id = blockIdx.x;
  const int nwg = gridDim.x;
  int swz = id;
  if ((nwg & 7) == 0) swz = (id & 7) * (nwg >> 3) + (id >> 3);
  const int band = gxTiles << 2;
  const int by = (swz & 3) + ((swz / band) << 2);
  const int bx = (swz >> 2) % gxTiles;
  const int m0 = by << 8;
  const int n0 = bx << 8;
  const int NT = K >> 6;

  // Per-thread staging source pointers, pre-permuted for the LDS XOR swizzle.
  const int kperm = ((l7 ^ l3) << 3);
  const unsigned short* aSrc[2][2];
  const unsigned short* bSrc[2][2];
#pragma unroll
  for (int h = 0; h < 2; ++h)
#pragma unroll
    for (int c = 0; c < 2; ++c) {
      const int rloc = h * 128 + wave * 16 + c * 8 + l3;
      aSrc[h][c] = A + (long long)(m0 + rloc) * lda + kperm;
      int bn = n0 + rloc;
      if (bn > N - 1) bn = N - 1;  // clamp: edge tiles read a valid row
      bSrc[h][c] = B + (long long)bn * ldb + kperm;
    }

  float4_t acc[8][4];
#pragma unroll
  for (int i = 0; i < 8; ++i)
#pragma unroll
    for (int j = 0; j < 4; ++j) acc[i][j] = (float4_t){0.f, 0.f, 0.f, 0.f};

  // Prologue: tile0 A+B -> buf0 (8 events), tile1 B -> buf1 (4 events).
  STAGE_A(0, 0, 0); STAGE_A(1, 0, 0);
  STAGE_B(0, 0, 0); STAGE_B(1, 0, 0);
  STAGE_B(0, 1, 1); STAGE_B(1, 1, 1);
  asm volatile("s_waitcnt vmcnt(4)" ::: "memory");  // tile0 landed
  __builtin_amdgcn_s_barrier();

  short8_t af[4][2], bf[4][2];
  for (int tt = 0; tt < NT; ++tt) {
    const int rb = tt & 1, nb = rb ^ 1;
    // ---- phase 1: (i0-3 x j0-3) @ kk0 (8 ds_read) ----
#pragma unroll
    for (int i = 0; i < 4; ++i) af[i][0] = LDA_FR(rb, i, 0);
#pragma unroll
    for (int j = 0; j < 4; ++j) bf[j][0] = LDB_FR(rb, j, 0);
    if (tt + 1 < NT) STAGE_A(0, tt + 1, nb);
    asm volatile("s_waitcnt lgkmcnt(4)" ::: "memory");
    __builtin_amdgcn_s_barrier();
    asm volatile("s_waitcnt lgkmcnt(0)" ::: "memory");
    __builtin_amdgcn_s_setprio(1);
#pragma unroll
    for (int i = 0; i < 4; ++i)
#pragma unroll
      for (int j = 0; j < 4; ++j) MFMA_ACC(acc[i][j], af[i][0], bf[j][0]);
    __builtin_amdgcn_s_setprio(0);
    __builtin_amdgcn_s_barrier();
    // ---- phase 2: (i0-3 x j0-3) @ kk1 (8 ds_read) ----
#pragma unroll
    for (int i = 0; i < 4; ++i) af[i][1] = LDA_FR(rb, i, 1);
#pragma unroll
    for (int j = 0; j < 4; ++j) bf[j][1] = LDB_FR(rb, j, 1);
    if (tt + 1 < NT) STAGE_A(1, tt + 1, nb);
    asm volatile("s_waitcnt lgkmcnt(4)" ::: "memory");
    __builtin_amdgcn_s_barrier();
    asm volatile("s_waitcnt lgkmcnt(0)" ::: "memory");
    __builtin_amdgcn_s_setprio(1);
#pragma unroll
    for (int i = 0; i < 4; ++i)
#pragma unroll
      for (int j = 0; j < 4; ++j) MFMA_ACC(acc[i][j], af[i][1], bf[j][1]);
    __builtin_amdgcn_s_setprio(0);
    __builtin_amdgcn_s_barrier();
    // ---- phase 3: (i4-7 x j0-3) @ kk0 (4 ds_read) ----
#pragma unroll
    for (int i = 0; i < 4; ++i) af[i][0] = LDA_FR(rb, 4 + i, 0);
    if (tt + 2 < NT) STAGE_B(0, tt + 2, rb);
    __builtin_amdgcn_s_barrier();
    asm volatile("s_waitcnt lgkmcnt(0)" ::: "memory");
    __builtin_amdgcn_s_setprio(1);
#pragma unroll
    for (int i = 0; i < 4; ++i)
#pragma unroll
      for (int j = 0; j < 4; ++j) MFMA_ACC(acc[4 + i][j], af[i][0], bf[j][0]);
    __builtin_amdgcn_s_setprio(0);
    __builtin_amdgcn_s_barrier();
    // ---- phase 4: (i4-7 x j0-3) @ kk1 (4 ds_read) ----
#pragma unroll
    for (int i = 0; i < 4; ++i) af[i][1] = LDA_FR(rb, 4 + i, 1);
    if (tt + 2 < NT) STAGE_B(1, tt + 2, rb);
    __builtin_amdgcn_s_barrier();
    asm volatile("s_waitcnt lgkmcnt(0)" ::: "memory");
    __builtin_amdgcn_s_setprio(1);
#pragma unroll
    for (int i = 0; i < 4; ++i)
#pragma unroll
      for (int j = 0; j < 4; ++j) MFMA_ACC(acc[4 + i][j], af[i][1], bf[j][1]);
    __builtin_amdgcn_s_setprio(0);
    if (tt < NT - 2) asm volatile("s_waitcnt vmcnt(4)" ::: "memory");
    else             asm volatile("s_waitcnt vmcnt(0)" ::: "memory");
    __builtin_amdgcn_s_barrier();
  }

  // Epilogue: D[m = quad*4+r][n = l16] per 16x16 tile.
#pragma unroll
  for (int i = 0; i < 8; ++i) {
#pragma unroll
    for (int r = 0; r < 4; ++r) {
      const int m = m0 + wm * 128 + i * 16 + quad * 4 + r;
      const long long cb = (long long)m * ldc;
#pragma unroll
      for (int j = 0; j < 4; ++j) {
        const int n = n0 + wn * 64 + j * 16 + l16;
        if (n < N) C[cb + n] = f2bf(acc[i][j][r]);
      }
    }
  }
}

// ---------------------------------------------------------------------------
// 128x128 2-phase MFMA GEMM, 2 blocks/CU (for odd-shaped tiles: in-proj tail,
// out-proj). One barrier per K-tile; t+1 staged at tile top.
// OUT_MODE: 0 bf16 out, 2 runtime (flags[fo] -> fp32).
// Requires M%128==0, K%64==0, grid == (M/128)*gxTiles.
// ---------------------------------------------------------------------------
#define LDA2(buf, i, kk) \
  (*(const short8_t*)&As2[(buf)*8192 + (wm*64 + (i)*16 + l16)*64 + \
                          (((((kk)<<2) + quad) ^ l7) << 3)])
#define LDB2(buf, j, kk) \
  (*(const short8_t*)&Bs2[(buf)*8192 + (wn*64 + (j)*16 + l16)*64 + \
                          (((((kk)<<2) + quad) ^ l7) << 3)])

template <int OUT_MODE>
__global__ __launch_bounds__(256, 2)
void gemm_2ph_k(const unsigned short* __restrict__ A,
                const unsigned short* __restrict__ B,
                void* __restrict__ Cptr,
                int N, int K, int lda, int ldb, int ldc, int gxTiles,
                const int* __restrict__ flags, int fo) {
  __shared__ alignas(16) unsigned short As2[2 * 128 * 64];
  __shared__ alignas(16) unsigned short Bs2[2 * 128 * 64];
  const int t = threadIdx.x;
  const int lane = t & 63;
  const int wave = t >> 6;   // 0..3
  const int quad = lane >> 4;
  const int l16 = lane & 15;
  const int l7 = lane & 7;
  const int l3 = lane >> 3;
  const int wm = wave >> 1;  // 0..1
  const int wn = wave & 1;   // 0..1
  const int ofp = (OUT_MODE == 2) ? flags[fo] : 0;

  // Banded XCD swizzle (bijective for nwg%8==0).
  int id = blockIdx.x;
  const int nwg = gridDim.x;
  int swz = id;
  if ((nwg & 7) == 0) swz = (id & 7) * (nwg >> 3) + (id >> 3);
  const int band = gxTiles << 2;
  const int by = (swz & 3) + ((swz / band) << 2);
  const int bx = (swz >> 2) % gxTiles;
  const int m0 = by << 7;
  const int n0 = bx << 7;
  const int NT = K >> 6;

  const int kperm = ((l7 ^ l3) << 3);
  const unsigned short* aSrc[4];
  const unsigned short* bSrc[4];
#pragma unroll
  for (int c = 0; c < 4; ++c) {
    aSrc[c] = A + (long long)(m0 + wave * 32 + c * 8 + l3) * lda + kperm;
    int bn = n0 + wave * 32 + c * 8 + l3;
    if (bn > N - 1) bn = N - 1;  // edge tiles read a valid row
    bSrc[c] = B + (long long)bn * ldb + kperm;
  }

  float4_t acc[4][4];
#pragma unroll
  for (int i = 0; i < 4; ++i)
#pragma unroll
    for (int j = 0; j < 4; ++j) acc[i][j] = (float4_t){0.f, 0.f, 0.f, 0.f};

#pragma unroll
  for (int c = 0; c < 4; ++c) {
    GLDS(aSrc[c], &As2[(wave * 32 + c * 8) * 64]);
    GLDS(bSrc[c], &Bs2[(wave * 32 + c * 8) * 64]);
  }
  asm volatile("s_waitcnt vmcnt(0)" ::: "memory");
  __builtin_amdgcn_s_barrier();

  short8_t af[4], bfr[4];
  for (int tt = 0; tt < NT; ++tt) {
    const int rb = tt & 1, nb = rb ^ 1;
#pragma unroll
    for (int i = 0; i < 4; ++i) af[i] = LDA2(rb, i, 0);
#pragma unroll
    for (int j = 0; j < 4; ++j) bfr[j] = LDB2(rb, j, 0);
    if (tt + 1 < NT) {
      const long long ko = (long long)(tt + 1) << 6;
#pragma unroll
      for (int c = 0; c < 4; ++c) {
        GLDS(aSrc[c] + ko, &As2[nb * 8192 + (wave * 32 + c * 8) * 64]);
        GLDS(bSrc[c] + ko, &Bs2[nb * 8192 + (wave * 32 + c * 8) * 64]);
      }
    }
    __builtin_amdgcn_s_setprio(1);
#pragma unroll
    for (int i = 0; i < 4; ++i)
#pragma unroll
      for (int j = 0; j < 4; ++j) MFMA_ACC(acc[i][j], af[i], bfr[j]);
    __builtin_amdgcn_s_setprio(0);
#pragma unroll
    for (int i = 0; i < 4; ++i) af[i] = LDA2(rb, i, 1);
#pragma unroll
    for (int j = 0; j < 4; ++j) bfr[j] = LDB2(rb, j, 1);
    __builtin_amdgcn_s_setprio(1);
#pragma unroll
    for (int i = 0; i < 4; ++i)
#pragma unroll
      for (int j = 0; j < 4; ++j) MFMA_ACC(acc[i][j], af[i], bfr[j]);
    __builtin_amdgcn_s_setprio(0);
    asm volatile("s_waitcnt vmcnt(0)" ::: "memory");
    __builtin_amdgcn_s_barrier();
  }

#pragma unroll
  for (int i = 0; i < 4; ++i) {
#pragma unroll
    for (int r = 0; r < 4; ++r) {
      const int m = m0 + wm * 64 + i * 16 + quad * 4 + r;
      const long long cb = (long long)m * ldc;
#pragma unroll
      for (int j = 0; j < 4; ++j) {
        const int n = n0 + wn * 64 + j * 16 + l16;
        if (n < N) {
          float v = acc[i][j][r];
          if (ofp) ((float*)Cptr)[cb + n] = v;
          else     ((unsigned short*)Cptr)[cb + n] = f2bf(v);
        }
      }
    }
  }
}

// ---------------------------------------------------------------------------
// Vector GEMM (small G = Cc@Bc^T batch). fp32 acc. OUT_MODE 1 = fp32 out.
// ---------------------------------------------------------------------------
template <int OUT_MODE>
__global__ __launch_bounds__(256)
void gemm_bt_k(const void* __restrict__ A, const void* __restrict__ B,
               void* __restrict__ Cptr, int M, int N, int K,
               int lda, int ldb, int ldc,
               long long sA, long long sB, long long sC,
               const int* __restrict__ flags, int fa, int fb, int fo) {
  __shared__ float As[128][20];
  __shared__ float Bs[128][20];
  const int t = threadIdx.x;
  const int tx = t & 15, ty = t >> 4;
  const int m0 = blockIdx.y * 128, n0 = blockIdx.x * 128;
  const int afp = flags[fa], bfp = flags[fb];
  const int ofp = (OUT_MODE == 2) ? flags[fo] : (OUT_MODE == 1);
  const long long zoff = (long long)blockIdx.z;
  float* Cf = (float*)Cptr + zoff * sC;
  unsigned short* Cb = (unsigned short*)Cptr + zoff * sC;

  float acc[8][8];
#pragma unroll
  for (int i = 0; i < 8; i++)
#pragma unroll
    for (int j = 0; j < 8; j++) acc[i][j] = 0.f;

  const int rowS = t >> 1;
  const int kof  = (t & 1) * 8;
  const long long aRow = zoff * sA + (long long)(m0 + rowS) * lda + kof;
  const long long bRow = zoff * sB + (long long)(n0 + rowS) * ldb + kof;
  const bool bOK = (n0 + rowS) < N;

  for (int k0 = 0; k0 < K; k0 += 16) {
    float af[8], bf[8];
    load8(A, aRow + k0, afp, af);
    if (bOK) load8(B, bRow + k0, bfp, bf);
    else { bf[0]=bf[1]=bf[2]=bf[3]=bf[4]=bf[5]=bf[6]=bf[7]=0.f; }
    __syncthreads();
    *(float4*)&As[rowS][kof]     = make_float4(af[0], af[1], af[2], af[3]);
    *(float4*)&As[rowS][kof + 4] = make_float4(af[4], af[5], af[6], af[7]);
    *(float4*)&Bs[rowS][kof]     = make_float4(bf[0], bf[1], bf[2], bf[3]);
    *(float4*)&Bs[rowS][kof + 4] = make_float4(bf[4], bf[5], bf[6], bf[7]);
    __syncthreads();
#pragma unroll
    for (int kk = 0; kk < 16; kk += 2) {
      float2 a2[8], b2[8];
#pragma unroll
      for (int i = 0; i < 8; i++) a2[i] = *(const float2*)&As[ty + 16 * i][kk];
#pragma unroll
      for (int j = 0; j < 8; j++) b2[j] = *(const float2*)&Bs[tx + 16 * j][kk];
#pragma unroll
      for (int i = 0; i < 8; i++)
#pragma unroll
        for (int j = 0; j < 8; j++) {
          acc[i][j] = fmaf(a2[i].x, b2[j].x, acc[i][j]);
          acc[i][j] = fmaf(a2[i].y, b2[j].y, acc[i][j]);
        }
    }
  }
#pragma unroll
  for (int i = 0; i < 8; i++) {
    const int m = m0 + ty + 16 * i;
    const long long base = (long long)m * ldc;
#pragma unroll
    for (int j = 0; j < 8; j++) {
      const int n = n0 + tx + 16 * j;
      if (n < N) {
        if (ofp) Cf[base + n] = acc[i][j];
        else     Cb[base + n] = f2bf(acc[i][j]);
      }
    }
  }
}

// ---------------------------------------------------------------------------
// Depthwise causal conv (K=4) + bias + SiLU over xBC columns of proj.
// ---------------------------------------------------------------------------
__global__ __launch_bounds__(256)
void conv_silu_k(const unsigned short* __restrict__ proj,
                 const void* __restrict__ cw,
                 const void* __restrict__ cb,
                 unsigned short* __restrict__ convx,
                 const int* __restrict__ flags) {
  const int total = B_SZ * L_SZ * (CONV_SZ / 4);
  int g = blockIdx.x * 256 + threadIdx.x;
  if (g >= total) return;
  const int fw = flags[2], fb = flags[3];
  int c4 = g % (CONV_SZ / 4);
  int bl = g / (CONV_SZ / 4);
  int l = bl & (L_SZ - 1);
  int ch = c4 * 4;
  float w0[8], w1[8];
  load8(cw, (long long)ch * 4, fw, w0);
  load8(cw, (long long)ch * 4 + 8, fw, w1);
  float accv[4];
  load4(cb, ch, fb, accv);
  float acc0 = accv[0], acc1 = accv[1], acc2 = accv[2], acc3 = accv[3];
  const long long rb = (long long)(bl - l);
#pragma unroll
  for (int k = 0; k < 4; k++) {
    int ls = l - 3 + k;
    if (ls < 0) continue;
    uint2 xv = *(const uint2*)(proj + (rb + ls) * PROJ_SZ + XOFF + ch);
    float x0 = bf2f((unsigned short)(xv.x & 0xffffu));
    float x1 = bf2f((unsigned short)(xv.x >> 16));
    float x2 = bf2f((unsigned short)(xv.y & 0xffffu));
    float x3 = bf2f((unsigned short)(xv.y >> 16));
    acc0 = fmaf(x0, w0[k], acc0);
    acc1 = fmaf(x1, w0[4 + k], acc1);
    acc2 = fmaf(x2, w1[k], acc2);
    acc3 = fmaf(x3, w1[4 + k], acc3);
  }
  unsigned short o0 = f2bf(silu_f(acc0));
  unsigned short o1 = f2bf(silu_f(acc1));
  unsigned short o2 = f2bf(silu_f(acc2));
  unsigned short o3 = f2bf(silu_f(acc3));
  *(uint2*)(convx + (long long)bl * CONV_SZ + ch) =
      make_uint2((unsigned int)o0 | ((unsigned int)o1 << 16),
                 (unsigned int)o2 | ((unsigned int)o3 << 16));
}

// ---------------------------------------------------------------------------
__global__ __launch_bounds__(256)
void dt_prep_k(const unsigned short* __restrict__ proj,
               const void* __restrict__ dt_bias,
               float* __restrict__ dtv, const int* __restrict__ flags) {
  int g = blockIdx.x * 256 + threadIdx.x;
  int h = g & 63;
  long long bl = g >> 6;
  float v = bf2f(proj[bl * PROJ_SZ + DTOFF + h]) + load1(dt_bias, h, flags[4]);
  float sp = (v > 20.f) ? v : log1pf(expf(v));
  dtv[g] = sp;
}

// ---------------------------------------------------------------------------
__global__ __launch_bounds__(256)
void acs_scan_k(const float* __restrict__ dtv,
                const void* __restrict__ A_log,
                float* __restrict__ acs, const int* __restrict__ flags) {
  __shared__ float sd[256];
  int blk = blockIdx.x;
  int h = blk & 63;
  int bc = blk >> 6;
  int l = threadIdx.x;
  float Ah = -expf(load1(A_log, h, flags[5]));
  long long row = (long long)bc * CH_SZ + l;
  sd[l] = Ah * dtv[row * NH_SZ + h];
  for (int off = 1; off < 256; off <<= 1) {
    __syncthreads();
    float tv = (l >= off) ? sd[l - off] : 0.f;
    __syncthreads();
    sd[l] += tv;
  }
  acs[(long long)blk * CH_SZ + l] = sd[l];
}

// ---------------------------------------------------------------------------
__global__ __launch_bounds__(256)
void chunk_states_k(const unsigned short* __restrict__ convx,
                    const float* __restrict__ dtv,
                    const float* __restrict__ acs,
                    float* __restrict__ stc) {
  __shared__ float Bw[32][128];
  __shared__ float xw[32][64];
  int blk = blockIdx.x;
  int h = blk & 63;
  int bc = blk >> 6;
  int t = threadIdx.x;
  const int p0 = (t & 15) * 4, n0 = (t >> 4) * 8;
  const float* acsb = acs + (long long)blk * 256;
  const float alast = acsb[255];
  float acc[4][8];
#pragma unroll
  for (int i = 0; i < 4; i++)
#pragma unroll
    for (int j = 0; j < 8; j++) acc[i][j] = 0.f;
  const long long row0 = (long long)bc * 256;

  for (int lt0 = 0; lt0 < 256; lt0 += 32) {
    __syncthreads();
#pragma unroll
    for (int q = 0; q < 4; q++) {
      int idx4 = (t + 256 * q) * 4;
      int r = idx4 >> 7, n = idx4 & 127;
      uint2 v = *(const uint2*)(convx + (row0 + lt0 + r) * CONV_SZ + BOFF + n);
      Bw[r][n]     = bf2f((unsigned short)(v.x & 0xffffu));
      Bw[r][n + 1] = bf2f((unsigned short)(v.x >> 16));
      Bw[r][n + 2] = bf2f((unsigned short)(v.y & 0xffffu));
      Bw[r][n + 3] = bf2f((unsigned short)(v.y >> 16));
    }
#pragma unroll
    for (int q = 0; q < 2; q++) {
      int idx4 = (t + 256 * q) * 4;
      int r = idx4 >> 6, p = idx4 & 63;
      long long lg = row0 + lt0 + r;
      float sc = dtv[lg * NH_SZ + h] * expf(alast - acsb[lt0 + r]);
      uint2 v = *(const uint2*)(convx + lg * CONV_SZ + h * 64 + p);
      xw[r][p]     = bf2f((unsigned short)(v.x & 0xffffu)) * sc;
      xw[r][p + 1] = bf2f((unsigned short)(v.x >> 16)) * sc;
      xw[r][p + 2] = bf2f((unsigned short)(v.y & 0xffffu)) * sc;
      xw[r][p + 3] = bf2f((unsigned short)(v.y >> 16)) * sc;
    }
    __syncthreads();
#pragma unroll 4
    for (int lt = 0; lt < 32; lt++) {
      float4 xv = *(const float4*)&xw[lt][p0];
      float4 b0 = *(const float4*)&Bw[lt][n0];
      float4 b1 = *(const float4*)&Bw[lt][n0 + 4];
      float xa[4] = {xv.x, xv.y, xv.z, xv.w};
      float ba[8] = {b0.x, b0.y, b0.z, b0.w, b1.x, b1.y, b1.z, b1.w};
#pragma unroll
      for (int i = 0; i < 4; i++)
#pragma unroll
        for (int j = 0; j < 8; j++) acc[i][j] = fmaf(xa[i], ba[j], acc[i][j]);
    }
  }
  float* outb = stc + (long long)blk * 8192;
#pragma unroll
  for (int i = 0; i < 4; i++) {
    *(float4*)&outb[(p0 + i) * 128 + n0] =
        make_float4(acc[i][0], acc[i][1], acc[i][2], acc[i][3]);
    *(float4*)&outb[(p0 + i) * 128 + n0 + 4] =
        make_float4(acc[i][4], acc[i][5], acc[i][6], acc[i][7]);
  }
}

// ---------------------------------------------------------------------------
__global__ __launch_bounds__(256)
void recur_k(float* __restrict__ stc, const float* __restrict__ acs) {
  int blk = blockIdx.x;
  int b = blk >> 6, h = blk & 63;
  int t = threadIdx.x;
  float S[32];
#pragma unroll
  for (int j = 0; j < 32; j++) S[j] = 0.f;
  for (int z = 0; z < 8; z++) {
    long long bz = ((long long)b * 8 + z) * 64 + h;
    long long base = bz * 8192;
    float e = expf(acs[bz * 256 + 255]);
#pragma unroll
    for (int j = 0; j < 32; j++) {
      int idx = j * 256 + t;
      float cs = stc[base + idx];
      stc[base + idx] = S[j];
      S[j] = fmaf(e, S[j], cs);
    }
  }
}

// ---------------------------------------------------------------------------
__global__ __launch_bounds__(256)
void yoff_k(const unsigned short* __restrict__ convx,
            const float* __restrict__ sti,
            const float* __restrict__ acs,
            const void* __restrict__ Dw,
            float* __restrict__ y, const int* __restrict__ flags) {
  __shared__ float SIt[128][68];
  __shared__ unsigned short Ct[64][128];
  int blk = blockIdx.x;
  int h = blk & 63;
  int bc = blk >> 6;
  int t = threadIdx.x;
  const int txp = t & 15, lq = t >> 4;
  const float Dh = load1(Dw, h, flags[6]);
  const float* sib = sti + (long long)blk * 8192;
#pragma unroll 4
  for (int q = 0; q < 32; q++) {
    int idx = t + 256 * q;
    SIt[idx & 127][idx >> 7] = sib[idx];
  }
  const float* acsb = acs + (long long)blk * 256;
  const long long row0 = (long long)bc * 256;
  for (int ltile = 0; ltile < 4; ltile++) {
    __syncthreads();
#pragma unroll 4
    for (int q = 0; q < 32; q++) {
      int idx = t + 256 * q;
      int lr = idx >> 7, n = idx & 127;
      Ct[lr][n] = convx[(row0 + ltile * 64 + lr) * CONV_SZ + COFF + n];
    }
    __syncthreads();
    float acc[4][4] = {};
#pragma unroll 4
    for (int n = 0; n < 128; n++) {
      float4 sv = *(const float4*)&SIt[n][txp * 4];
      float c0 = bf2f(Ct[lq * 4 + 0][n]);
      float c1 = bf2f(Ct[lq * 4 + 1][n]);
      float c2 = bf2f(Ct[lq * 4 + 2][n]);
      float c3 = bf2f(Ct[lq * 4 + 3][n]);
      acc[0][0] = fmaf(c0, sv.x, acc[0][0]); acc[0][1] = fmaf(c0, sv.y, acc[0][1]);
      acc[0][2] = fmaf(c0, sv.z, acc[0][2]); acc[0][3] = fmaf(c0, sv.w, acc[0][3]);
      acc[1][0] = fmaf(c1, sv.x, acc[1][0]); acc[1][1] = fmaf(c1, sv.y, acc[1][1]);
      acc[1][2] = fmaf(c1, sv.z, acc[1][2]); acc[1][3] = fmaf(c1, sv.w, acc[1][3]);
      acc[2][0] = fmaf(c2, sv.x, acc[2][0]); acc[2][1] = fmaf(c2, sv.y, acc[2][1]);
      acc[2][2] = fmaf(c2, sv.z, acc[2][2]); acc[2][3] = fmaf(c2, sv.w, acc[2][3]);
      acc[3][0] = fmaf(c3, sv.x, acc[3][0]); acc[3][1] = fmaf(c3, sv.y, acc[3][1]);
      acc[3][2] = fmaf(c3, sv.z, acc[3][2]); acc[3][3] = fmaf(c3, sv.w, acc[3][3]);
    }
#pragma unroll
    for (int i = 0; i < 4; i++) {
      int lloc = ltile * 64 + lq * 4 + i;
      long long row = row0 + lloc;
      float ex = expf(acsb[lloc]);
      uint2 xv = *(const uint2*)(convx + row * CONV_SZ + h * 64 + txp * 4);
      float4 o;
      o.x = fmaf(ex, acc[i][0], Dh * bf2f((unsigned short)(xv.x & 0xffffu)));
      o.y = fmaf(ex, acc[i][1], Dh * bf2f((unsigned short)(xv.x >> 16)));
      o.z = fmaf(ex, acc[i][2], Dh * bf2f((unsigned short)(xv.y & 0xffffu)));
      o.w = fmaf(ex, acc[i][3], Dh * bf2f((unsigned short)(xv.y >> 16)));
      *(float4*)&y[row * I_SZ + h * 64 + txp * 4] = o;
    }
  }
}

// ---------------------------------------------------------------------------
__global__ __launch_bounds__(256)
void ydiag_k(const unsigned short* __restrict__ convx,
             const float* __restrict__ dtv,
             const float* __restrict__ acs,
             const float* __restrict__ Gmat,
             float* __restrict__ y) {
  __shared__ float acs_s[256];
  __shared__ float xsT[64][68];
  __shared__ float Mt[64][66];
  int blk = blockIdx.x;
  int h = blk & 63;
  int bc = blk >> 6;
  int t = threadIdx.x;
  const int txp = t & 15, lq = t >> 4;
  acs_s[t] = acs[(long long)blk * 256 + t];
  const long long row0 = (long long)bc * 256;
  const float* Gb = Gmat + (long long)bc * 65536;
  for (int ltile = 0; ltile < 4; ltile++) {
    float acc[4][4] = {};
    for (int stile = 0; stile <= ltile; stile++) {
      __syncthreads();
#pragma unroll 4
      for (int q = 0; q < 16; q++) {
        int idx = t + 256 * q;
        int ss = idx >> 6, p = idx & 63;
        long long row = row0 + stile * 64 + ss;
        xsT[ss][p] = bf2f(convx[row * CONV_SZ + h * 64 + p]) * dtv[row * NH_SZ + h];
      }
#pragma unroll 4
      for (int q = 0; q < 16; q++) {
        int idx = t + 256 * q;
        int lr = idx >> 6, ss = idx & 63;
        int lg = ltile * 64 + lr, sg = stile * 64 + ss;
        float m = 0.f;
        if (sg <= lg) m = Gb[(long long)lg * 256 + sg] * expf(acs_s[lg] - acs_s[sg]);
        Mt[lr][ss] = m;
      }
      __syncthreads();
#pragma unroll 4
      for (int ss = 0; ss < 64; ss++) {
        float4 xv = *(const float4*)&xsT[ss][txp * 4];
        float m0 = Mt[lq * 4 + 0][ss];
        float m1 = Mt[lq * 4 + 1][ss];
        float m2 = Mt[lq * 4 + 2][ss];
        float m3 = Mt[lq * 4 + 3][ss];
        acc[0][0] = fmaf(m0, xv.x, acc[0][0]); acc[0][1] = fmaf(m0, xv.y, acc[0][1]);
        acc[0][2] = fmaf(m0, xv.z, acc[0][2]); acc[0][3] = fmaf(m0, xv.w, acc[0][3]);
        acc[1][0] = fmaf(m1, xv.x, acc[1][0]); acc[1][1] = fmaf(m1, xv.y, acc[1][1]);
        acc[1][2] = fmaf(m1, xv.z, acc[1][2]); acc[1][3] = fmaf(m1, xv.w, acc[1][3]);
        acc[2][0] = fmaf(m2, xv.x, acc[2][0]); acc[2][1] = fmaf(m2, xv.y, acc[2][1]);
        acc[2][2] = fmaf(m2, xv.z, acc[2][2]); acc[2][3] = fmaf(m2, xv.w, acc[2][3]);
        acc[3][0] = fmaf(m3, xv.x, acc[3][0]); acc[3][1] = fmaf(m3, xv.y, acc[3][1]);
        acc[3][2] = fmaf(m3, xv.z, acc[3][2]); acc[3][3] = fmaf(m3, xv.w, acc[3][3]);
      }
    }
#pragma unroll
    for (int i = 0; i < 4; i++) {
      long long row = row0 + ltile * 64 + lq * 4 + i;
      float* yp = &y[row * I_SZ + h * 64 + txp * 4];
      float4 cur = *(float4*)yp;
      cur.x += acc[i][0]; cur.y += acc[i][1]; cur.z += acc[i][2]; cur.w += acc[i][3];
      *(float4*)yp = cur;
    }
  }
}

// ---------------------------------------------------------------------------
__global__ __launch_bounds__(256)
void norm_k(const float* __restrict__ y,
            const unsigned short* __restrict__ proj,
            const void* __restrict__ nw,
            unsigned short* __restrict__ yfb, const int* __restrict__ flags) {
  __shared__ float red[4];
  __shared__ float sc_s;
  int row = blockIdx.x;
  int t = threadIdx.x;
  const int fn = flags[7];
  const float* yr = y + (long long)row * I_SZ;
  const unsigned short* zr = proj + (long long)row * PROJ_SZ;
  float g[16];
  float ss = 0.f;
#pragma unroll
  for (int q = 0; q < 4; q++) {
    int i0 = q * 1024 + t * 4;
    float4 yv = *(const float4*)&yr[i0];
    uint2 zv = *(const uint2*)&zr[i0];
    float z0 = bf2f((unsigned short)(zv.x & 0xffffu));
    float z1 = bf2f((unsigned short)(zv.x >> 16));
    float z2 = bf2f((unsigned short)(zv.y & 0xffffu));
    float z3 = bf2f((unsigned short)(zv.y >> 16));
    float g0 = yv.x * silu_f(z0), g1 = yv.y * silu_f(z1);
    float g2 = yv.z * silu_f(z2), g3 = yv.w * silu_f(z3);
    g[q * 4 + 0] = g0; g[q * 4 + 1] = g1; g[q * 4 + 2] = g2; g[q * 4 + 3] = g3;
    ss += g0 * g0 + g1 * g1 + g2 * g2 + g3 * g3;
  }
#pragma unroll
  for (int off = 32; off > 0; off >>= 1) ss += __shfl_down(ss, off, 64);
  if ((t & 63) == 0) red[t >> 6] = ss;
  __syncthreads();
  if (t == 0) sc_s = rsqrtf((red[0] + red[1] + red[2] + red[3]) * (1.f / 4096.f) + 1e-5f);
  __syncthreads();
  float sc = sc_s;
#pragma unroll
  for (int q = 0; q < 4; q++) {
    int i0 = q * 1024 + t * 4;
    float nv[4];
    load4(nw, i0, fn, nv);
    unsigned short o0 = f2bf(g[q * 4 + 0] * sc * nv[0]);
    unsigned short o1 = f2bf(g[q * 4 + 1] * sc * nv[1]);
    unsigned short o2 = f2bf(g[q * 4 + 2] * sc * nv[2]);
    unsigned short o3 = f2bf(g[q * 4 + 3] * sc * nv[3]);
    *(uint2*)&yfb[(long long)row * I_SZ + i0] =
        make_uint2((unsigned int)o0 | ((unsigned int)o1 << 16),
                   (unsigned int)o2 | ((unsigned int)o3 << 16));
  }
}

// ---------------------------------------------------------------------------
extern "C" void kernel_launch(void* const* d_in, const int* in_sizes, int n_in,
                              void* d_out, int out_size, void* d_ws, size_t ws_size,
                              hipStream_t stream) {
  const void* hs     = d_in[0];
  const void* W_in   = d_in[1];
  const void* conv_w = d_in[2];
  const void* conv_b = d_in[3];
  const void* dt_b   = d_in[4];
  const void* A_log  = d_in[5];
  const void* Dw     = d_in[6];
  const void* nw     = d_in[7];
  const void* W_out  = d_in[8];

  char* ws = (char*)d_ws;
  size_t off = 0;
  auto alloc = [&](size_t bytes) -> void* {
    void* p = ws + off;
    off += (bytes + 255) & ~(size_t)255;
    return p;
  };
  const long long ML = (long long)B_SZ * L_SZ;  // 4096 rows
  int* flags = (int*)alloc(64);
  unsigned short* proj  = (unsigned short*)alloc(ML * PROJ_SZ * 2);             // 66.5 MB
  unsigned short* convx = (unsigned short*)alloc(ML * CONV_SZ * 2);             // 34 MB
  float* dtv  = (float*)alloc(ML * NH_SZ * 4);                                  // 1 MB
  float* acsb = (float*)alloc((long long)B_SZ * NC_SZ * NH_SZ * CH_SZ * 4);     // 1 MB
  float* Gm   = (float*)alloc((long long)B_SZ * NC_SZ * CH_SZ * CH_SZ * 4);     // 4 MB
  float* stc  = (float*)alloc((long long)B_SZ * NC_SZ * NH_SZ * P_SZ * N_SZ * 4);  // 32 MB
  float* yb   = (float*)alloc(ML * I_SZ * 4);                                   // 64 MB
  unsigned short* yfb = (unsigned short*)stc;  // alias: stc dead after yoff_k
  // bf16 staging copies alias the yb region (dead until yoff_k / after norm_k)
  unsigned short* hs_bf   = (unsigned short*)yb;                 // 16 MB
  unsigned short* Win_bf  = (unsigned short*)yb + 8388608;       // 34.9 MB (ends <51MB)
  unsigned short* Wout_bf = (unsigned short*)yb;                 // 16 MB (after norm_k)
  (void)n_in; (void)out_size;
  if (off > ws_size) return;

  dim3 blk(256);
  // 0. per-tensor dtype detection
  detect_k<<<1, blk, 0, stream>>>(hs, W_in, conv_w, conv_b, dt_b, A_log, Dw, nw, W_out,
                                  in_sizes[0], in_sizes[1], in_sizes[2], in_sizes[3],
                                  in_sizes[4], in_sizes[5], in_sizes[6], in_sizes[7],
                                  in_sizes[8], flags);
  // 0a. convert hs, W_in to packed bf16
  cvt_bf16_k<<<dim3(4096), blk, 0, stream>>>(hs, hs_bf, 1048576LL, flags, 0);
  cvt_bf16_k<<<dim3(8512), blk, 0, stream>>>(W_in, Win_bf, 2179072LL, flags, 1);
  // 1. in-proj: proj[4096,8512] = hs @ W_in^T  (bf16 out)
  //    cols 0..8191 via 256^2 8-phase (512 blocks = exactly 2 rounds @ 1/CU)
  gemm_8ph_k<<<dim3(512), dim3(512), 0, stream>>>(
      hs_bf, Win_bf, proj, PROJ_SZ, H_SZ, H_SZ, H_SZ, PROJ_SZ, /*gxTiles=*/32);
  //    cols 8192..8511 (320 cols) via 2ph (grid 32x3 = 96 blocks, 2/CU)
  gemm_2ph_k<0><<<dim3(96), blk, 0, stream>>>(
      hs_bf, Win_bf + 8192LL * 2048, proj + 8192, 320, H_SZ,
      H_SZ, H_SZ, PROJ_SZ, /*gxTiles=*/3, flags, 15);
  // 2. conv + silu
  conv_silu_k<<<dim3((B_SZ * L_SZ * (CONV_SZ / 4) + 255) / 256), blk, 0, stream>>>(
      proj, conv_w, conv_b, convx, flags);
  // 3. dt
  dt_prep_k<<<dim3((unsigned)(ML * NH_SZ / 256)), blk, 0, stream>>>(proj, dt_b, dtv, flags);
  // 4. cumsum A*dt
  acs_scan_k<<<dim3(B_SZ * NC_SZ * NH_SZ), blk, 0, stream>>>(dtv, A_log, acsb, flags);
  // 5. G = Cc @ Bc^T per (b,chunk)  (fp32 out, vector path)
  gemm_bt_k<1><<<dim3(2, 2, 16), blk, 0, stream>>>(
      (const unsigned short*)convx + COFF, (const unsigned short*)convx + BOFF,
      Gm, 256, 256, 128, CONV_SZ, CONV_SZ, 256,
      (long long)256 * CONV_SZ, (long long)256 * CONV_SZ, 65536,
      flags, 15, 15, 15);
  // 6. per-chunk states
  chunk_states_k<<<dim3(1024), blk, 0, stream>>>(convx, dtv, acsb, stc);
  // 7. inter-chunk recurrence (in-place on stc)
  recur_k<<<dim3(B_SZ * NH_SZ), blk, 0, stream>>>(stc, acsb);
  // 8. Y_off + D*x  (overwrites yb; hs_bf/Win_bf dead)
  yoff_k<<<dim3(1024), blk, 0, stream>>>(convx, stc, acsb, Dw, yb, flags);
  // 9. Y_diag
  ydiag_k<<<dim3(1024), blk, 0, stream>>>(convx, dtv, acsb, Gm, yb);
  // 10. gated RMSNorm
  norm_k<<<dim3((unsigned)ML), blk, 0, stream>>>(yb, proj, nw, yfb, flags);
  // 10a. convert W_out (yb now dead)
  cvt_bf16_k<<<dim3(4096), blk, 0, stream>>>(W_out, Wout_bf, 1048576LL, flags, 8);
  // 11. out-proj: out = yf @ W_out^T, grid 32x16 = 512 blocks = 1 round of
  //     2 blocks/CU. Output dtype follows hs flag.
  gemm_2ph_k<2><<<dim3(512), blk, 0, stream>>>(
      yfb, Wout_bf, d_out, H_SZ, I_SZ, I_SZ, I_SZ, H_SZ, /*gxTiles=*/16,
      flags, 0);
}

// Round 7
// 677.805 us; speedup vs baseline: 1.1799x; 1.0724x over previous
//
#include <hip/hip_runtime.h>
#include <hip/hip_bf16.h>
#include <math.h>

// ---------------------------------------------------------------------------
// Mamba2 mixer forward, MI355X. Round 13: MFMA-ize yoff + G (clean-layout).
// R12: 727us (best). Middle ~480us VALU. This round converts the two middle
// GEMMs with K-contiguous row-major operands (no transpose staging):
//  - yoff_mfma_k: Y_off[l][p] = sum_n C[l][n]*st[p][n]. A=C bf16 from convx
//    (exact), B=states fp32->bf16 in-register (only new quantization). Zero
//    LDS, direct-global fragments, 1024 blocks.
//  - gemm_g_k: G[l][s] = sum_n C[l][n]*B[s][n]. Both operands already bf16
//    in convx, fp32 accum -> precision-neutral; replaces 64-block vector
//    gemm_bt (removed).
// chunk_states/ydiag (transposed operands) deferred pending absmax verdict.
// ---------------------------------------------------------------------------

#define B_SZ 2
#define L_SZ 2048
#define H_SZ 2048
#define I_SZ 4096
#define N_SZ 128
#define NH_SZ 64
#define P_SZ 64
#define CH_SZ 256
#define NC_SZ 8
#define PROJ_SZ 8512
#define CONV_SZ 4352
#define XOFF 4096   // xBC start inside proj row
#define DTOFF 8448  // dt start inside proj row
#define BOFF 4096   // B start inside convx row
#define COFF 4224   // C start inside convx row

typedef __attribute__((ext_vector_type(8))) short short8_t;   // 8 bf16 frag
typedef __attribute__((ext_vector_type(4))) float float4_t;   // MFMA acc

// Direct-to-LDS DMA, 16 B per lane, wave-uniform LDS base.
#define GLDS(gp, lp)                                                   \
  __builtin_amdgcn_global_load_lds(                                    \
      (const __attribute__((address_space(1))) void*)(gp),             \
      (__attribute__((address_space(3))) void*)(lp), 16, 0, 0)

__device__ __forceinline__ float bf2f(unsigned short u) {
  union { unsigned int i; float f; } v; v.i = ((unsigned int)u) << 16; return v.f;
}
__device__ __forceinline__ unsigned short f2bf(float f) {
  union { float f; unsigned int i; } v; v.f = f;
  unsigned int b = v.i + 0x7fffu + ((v.i >> 16) & 1u);
  return (unsigned short)(b >> 16);
}
__device__ __forceinline__ void unpack8(uint4 v, float* f) {
  f[0] = bf2f((unsigned short)(v.x & 0xffffu)); f[1] = bf2f((unsigned short)(v.x >> 16));
  f[2] = bf2f((unsigned short)(v.y & 0xffffu)); f[3] = bf2f((unsigned short)(v.y >> 16));
  f[4] = bf2f((unsigned short)(v.z & 0xffffu)); f[5] = bf2f((unsigned short)(v.z >> 16));
  f[6] = bf2f((unsigned short)(v.w & 0xffffu)); f[7] = bf2f((unsigned short)(v.w >> 16));
}
__device__ __forceinline__ float silu_f(float x) { return x / (1.f + expf(-x)); }

__device__ __forceinline__ float load1(const void* p, long long e, int fp32) {
  return fp32 ? ((const float*)p)[e] : bf2f(((const unsigned short*)p)[e]);
}
__device__ __forceinline__ void load4(const void* p, long long e, int fp32, float* f) {
  if (fp32) {
    float4 a = *(const float4*)((const float*)p + e);
    f[0] = a.x; f[1] = a.y; f[2] = a.z; f[3] = a.w;
  } else {
    uint2 v = *(const uint2*)((const unsigned short*)p + e);
    f[0] = bf2f((unsigned short)(v.x & 0xffffu)); f[1] = bf2f((unsigned short)(v.x >> 16));
    f[2] = bf2f((unsigned short)(v.y & 0xffffu)); f[3] = bf2f((unsigned short)(v.y >> 16));
  }
}
__device__ __forceinline__ void load8(const void* p, long long e, int fp32, float* f) {
  if (fp32) {
    float4 a = *(const float4*)((const float*)p + e);
    float4 b = *(const float4*)((const float*)p + e + 4);
    f[0] = a.x; f[1] = a.y; f[2] = a.z; f[3] = a.w;
    f[4] = b.x; f[5] = b.y; f[6] = b.z; f[7] = b.w;
  } else {
    uint4 v = *(const uint4*)((const unsigned short*)p + e);
    unpack8(v, f);
  }
}
// fp32x8 -> bf16x8 fragment (in-register conversion for MFMA B operand).
__device__ __forceinline__ short8_t pack_bf8(const float* p) {
  float4 a = *(const float4*)p;
  float4 b = *(const float4*)(p + 4);
  short8_t r;
  r[0] = (short)f2bf(a.x); r[1] = (short)f2bf(a.y);
  r[2] = (short)f2bf(a.z); r[3] = (short)f2bf(a.w);
  r[4] = (short)f2bf(b.x); r[5] = (short)f2bf(b.y);
  r[6] = (short)f2bf(b.z); r[7] = (short)f2bf(b.w);
  return r;
}

// ---------------------------------------------------------------------------
// Per-tensor dtype detector (confirmed working R3/R4).
// ---------------------------------------------------------------------------
__global__ void detect_k(const void* p0, const void* p1, const void* p2,
                         const void* p3, const void* p4, const void* p5,
                         const void* p6, const void* p7, const void* p8,
                         int n0, int n1, int n2, int n3, int n4, int n5,
                         int n6, int n7, int n8, int* flags) {
  __shared__ int pe, po;
  const void* ps[9] = {p0, p1, p2, p3, p4, p5, p6, p7, p8};
  int ns[9] = {n0, n1, n2, n3, n4, n5, n6, n7, n8};
  int t = threadIdx.x;
  for (int i = 0; i < 9; i++) {
    if (t == 0) { pe = 0; po = 0; }
    __syncthreads();
    int S = ns[i] < 256 ? ns[i] : 256;
    if (t < S) {
      unsigned short u = ((const unsigned short*)ps[i])[t];
      int ex = (u >> 7) & 0xFF;
      int plaus = ((u & 0x7FFFu) != 0) && (ex >= 0x70) && (ex <= 0x8F);
      if (plaus) { if (t & 1) atomicAdd(&po, 1); else atomicAdd(&pe, 1); }
    }
    __syncthreads();
    if (t == 0) flags[i] = (2 * pe < po) ? 1 : 0;
    __syncthreads();
  }
  if (t == 0) { flags[14] = 0; flags[15] = 0; }  // internal buffers: bf16
}

// ---------------------------------------------------------------------------
// fp32 (or bf16 passthrough) -> packed bf16. 8 elems/thread. n8 = n/8.
// ---------------------------------------------------------------------------
__global__ __launch_bounds__(256)
void cvt_bf16_k(const void* __restrict__ src, unsigned short* __restrict__ dst,
                long long n8, const int* __restrict__ flags, int fi) {
  long long g = (long long)blockIdx.x * 256 + threadIdx.x;
  if (g >= n8) return;
  long long e = g * 8;
  if (flags[fi]) {
    const float* s = (const float*)src + e;
    float4 a = *(const float4*)s;
    float4 b = *(const float4*)(s + 4);
    unsigned short o[8] = {f2bf(a.x), f2bf(a.y), f2bf(a.z), f2bf(a.w),
                           f2bf(b.x), f2bf(b.y), f2bf(b.z), f2bf(b.w)};
    *(uint4*)(dst + e) = *(const uint4*)o;
  } else {
    *(uint4*)(dst + e) = *(const uint4*)((const unsigned short*)src + e);
  }
}

// ---------------------------------------------------------------------------
// 256x256 8-phase MFMA GEMM (measured 137us on in-proj main).
// Phases paired by kk-slice (8/8/4/4 read profile); 16 MFMA/phase.
// vmcnt(4) once per tile; LDS XOR swizzle via pre-permuted global source.
// Requires M%256==0, K%64==0, grid == (M/256)*gxTiles, nwg%8==0.
// ---------------------------------------------------------------------------
#define MFMA_ACC(d, a, b) \
  d = __builtin_amdgcn_mfma_f32_16x16x32_bf16(a, b, d, 0, 0, 0)
#define LDA_FR(buf, i, kk) \
  (*(const short8_t*)&As[(buf)*16384 + (wm*128 + (i)*16 + l16)*64 + \
                         (((((kk)<<2) + quad) ^ l7) << 3)])
#define LDB_FR(buf, j, kk) \
  (*(const short8_t*)&Bs[(buf)*16384 + (wn*64 + (j)*16 + l16)*64 + \
                         (((((kk)<<2) + quad) ^ l7) << 3)])
#define STAGE_A(h, tile, buf) do {                                          \
    GLDS(aSrc[h][0] + ((long long)(tile) << 6),                             \
         &As[(buf)*16384 + (h)*8192 + (wave*16)*64]);                       \
    GLDS(aSrc[h][1] + ((long long)(tile) << 6),                             \
         &As[(buf)*16384 + (h)*8192 + (wave*16 + 8)*64]);                   \
  } while (0)
#define STAGE_B(h, tile, buf) do {                                          \
    GLDS(bSrc[h][0] + ((long long)(tile) << 6),                             \
         &Bs[(buf)*16384 + (h)*8192 + (wave*16)*64]);                       \
    GLDS(bSrc[h][1] + ((long long)(tile) << 6),                             \
         &Bs[(buf)*16384 + (h)*8192 + (wave*16 + 8)*64]);                   \
  } while (0)

__global__ __launch_bounds__(512, 2)
void gemm_8ph_k(const unsigned short* __restrict__ A,
                const unsigned short* __restrict__ B,
                unsigned short* __restrict__ C,
                int N, int K, int lda, int ldb, int ldc, int gxTiles) {
  __shared__ alignas(16) unsigned short As[2 * 256 * 64];
  __shared__ alignas(16) unsigned short Bs[2 * 256 * 64];
  const int t = threadIdx.x;
  const int lane = t & 63;
  const int wave = t >> 6;
  const int quad = lane >> 4;
  const int l16 = lane & 15;
  const int l7 = lane & 7;
  const int l3 = lane >> 3;
  const int wm = wave >> 2;   // 0..1
  const int wn = wave & 3;    // 0..3

  // T1: banded XCD swizzle.
  int id = blockIdx.x;
  const int nwg = gridDim.x;
  int swz = id;
  if ((nwg & 7) == 0) swz = (id & 7) * (nwg >> 3) + (id >> 3);
  const int band = gxTiles << 2;
  const int by = (swz & 3) + ((swz / band) << 2);
  const int bx = (swz >> 2) % gxTiles;
  const int m0 = by << 8;
  const int n0 = bx << 8;
  const int NT = K >> 6;

  // Per-thread staging source pointers, pre-permuted for the LDS XOR swizzle.
  const int kperm = ((l7 ^ l3) << 3);
  const unsigned short* aSrc[2][2];
  const unsigned short* bSrc[2][2];
#pragma unroll
  for (int h = 0; h < 2; ++h)
#pragma unroll
    for (int c = 0; c < 2; ++c) {
      const int rloc = h * 128 + wave * 16 + c * 8 + l3;
      aSrc[h][c] = A + (long long)(m0 + rloc) * lda + kperm;
      int bn = n0 + rloc;
      if (bn > N - 1) bn = N - 1;  // clamp: edge tiles read a valid row
      bSrc[h][c] = B + (long long)bn * ldb + kperm;
    }

  float4_t acc[8][4];
#pragma unroll
  for (int i = 0; i < 8; ++i)
#pragma unroll
    for (int j = 0; j < 4; ++j) acc[i][j] = (float4_t){0.f, 0.f, 0.f, 0.f};

  // Prologue: tile0 A+B -> buf0 (8 events), tile1 B -> buf1 (4 events).
  STAGE_A(0, 0, 0); STAGE_A(1, 0, 0);
  STAGE_B(0, 0, 0); STAGE_B(1, 0, 0);
  STAGE_B(0, 1, 1); STAGE_B(1, 1, 1);
  asm volatile("s_waitcnt vmcnt(4)" ::: "memory");  // tile0 landed
  __builtin_amdgcn_s_barrier();

  short8_t af[4][2], bf[4][2];
  for (int tt = 0; tt < NT; ++tt) {
    const int rb = tt & 1, nb = rb ^ 1;
    // ---- phase 1: (i0-3 x j0-3) @ kk0 (8 ds_read) ----
#pragma unroll
    for (int i = 0; i < 4; ++i) af[i][0] = LDA_FR(rb, i, 0);
#pragma unroll
    for (int j = 0; j < 4; ++j) bf[j][0] = LDB_FR(rb, j, 0);
    if (tt + 1 < NT) STAGE_A(0, tt + 1, nb);
    asm volatile("s_waitcnt lgkmcnt(4)" ::: "memory");
    __builtin_amdgcn_s_barrier();
    asm volatile("s_waitcnt lgkmcnt(0)" ::: "memory");
    __builtin_amdgcn_s_setprio(1);
#pragma unroll
    for (int i = 0; i < 4; ++i)
#pragma unroll
      for (int j = 0; j < 4; ++j) MFMA_ACC(acc[i][j], af[i][0], bf[j][0]);
    __builtin_amdgcn_s_setprio(0);
    __builtin_amdgcn_s_barrier();
    // ---- phase 2: (i0-3 x j0-3) @ kk1 (8 ds_read) ----
#pragma unroll
    for (int i = 0; i < 4; ++i) af[i][1] = LDA_FR(rb, i, 1);
#pragma unroll
    for (int j = 0; j < 4; ++j) bf[j][1] = LDB_FR(rb, j, 1);
    if (tt + 1 < NT) STAGE_A(1, tt + 1, nb);
    asm volatile("s_waitcnt lgkmcnt(4)" ::: "memory");
    __builtin_amdgcn_s_barrier();
    asm volatile("s_waitcnt lgkmcnt(0)" ::: "memory");
    __builtin_amdgcn_s_setprio(1);
#pragma unroll
    for (int i = 0; i < 4; ++i)
#pragma unroll
      for (int j = 0; j < 4; ++j) MFMA_ACC(acc[i][j], af[i][1], bf[j][1]);
    __builtin_amdgcn_s_setprio(0);
    __builtin_amdgcn_s_barrier();
    // ---- phase 3: (i4-7 x j0-3) @ kk0 (4 ds_read) ----
#pragma unroll
    for (int i = 0; i < 4; ++i) af[i][0] = LDA_FR(rb, 4 + i, 0);
    if (tt + 2 < NT) STAGE_B(0, tt + 2, rb);
    __builtin_amdgcn_s_barrier();
    asm volatile("s_waitcnt lgkmcnt(0)" ::: "memory");
    __builtin_amdgcn_s_setprio(1);
#pragma unroll
    for (int i = 0; i < 4; ++i)
#pragma unroll
      for (int j = 0; j < 4; ++j) MFMA_ACC(acc[4 + i][j], af[i][0], bf[j][0]);
    __builtin_amdgcn_s_setprio(0);
    __builtin_amdgcn_s_barrier();
    // ---- phase 4: (i4-7 x j0-3) @ kk1 (0 extra B reads) ----
#pragma unroll
    for (int i = 0; i < 4; ++i) af[i][1] = LDA_FR(rb, 4 + i, 1);
    if (tt + 2 < NT) STAGE_B(1, tt + 2, rb);
    __builtin_amdgcn_s_barrier();
    asm volatile("s_waitcnt lgkmcnt(0)" ::: "memory");
    __builtin_amdgcn_s_setprio(1);
#pragma unroll
    for (int i = 0; i < 4; ++i)
#pragma unroll
      for (int j = 0; j < 4; ++j) MFMA_ACC(acc[4 + i][j], af[i][1], bf[j][1]);
    __builtin_amdgcn_s_setprio(0);
    if (tt < NT - 2) asm volatile("s_waitcnt vmcnt(4)" ::: "memory");
    else             asm volatile("s_waitcnt vmcnt(0)" ::: "memory");
    __builtin_amdgcn_s_barrier();
  }

  // Epilogue: D[m = quad*4+r][n = l16] per 16x16 tile.
#pragma unroll
  for (int i = 0; i < 8; ++i) {
#pragma unroll
    for (int r = 0; r < 4; ++r) {
      const int m = m0 + wm * 128 + i * 16 + quad * 4 + r;
      const long long cb = (long long)m * ldc;
#pragma unroll
      for (int j = 0; j < 4; ++j) {
        const int n = n0 + wn * 64 + j * 16 + l16;
        if (n < N) C[cb + n] = f2bf(acc[i][j][r]);
      }
    }
  }
}

// ---------------------------------------------------------------------------
// 128x128 2-phase MFMA GEMM, 2 blocks/CU (for odd-shaped tiles: in-proj tail,
// out-proj). One barrier per K-tile; t+1 staged at tile top.
// OUT_MODE: 0 bf16 out, 2 runtime (flags[fo] -> fp32).
// Requires M%128==0, K%64==0, grid == (M/128)*gxTiles.
// ---------------------------------------------------------------------------
#define LDA2(buf, i, kk) \
  (*(const short8_t*)&As2[(buf)*8192 + (wm*64 + (i)*16 + l16)*64 + \
                          (((((kk)<<2) + quad) ^ l7) << 3)])
#define LDB2(buf, j, kk) \
  (*(const short8_t*)&Bs2[(buf)*8192 + (wn*64 + (j)*16 + l16)*64 + \
                          (((((kk)<<2) + quad) ^ l7) << 3)])

template <int OUT_MODE>
__global__ __launch_bounds__(256, 2)
void gemm_2ph_k(const unsigned short* __restrict__ A,
                const unsigned short* __restrict__ B,
                void* __restrict__ Cptr,
                int N, int K, int lda, int ldb, int ldc, int gxTiles,
                const int* __restrict__ flags, int fo) {
  __shared__ alignas(16) unsigned short As2[2 * 128 * 64];
  __shared__ alignas(16) unsigned short Bs2[2 * 128 * 64];
  const int t = threadIdx.x;
  const int lane = t & 63;
  const int wave = t >> 6;   // 0..3
  const int quad = lane >> 4;
  const int l16 = lane & 15;
  const int l7 = lane & 7;
  const int l3 = lane >> 3;
  const int wm = wave >> 1;  // 0..1
  const int wn = wave & 1;   // 0..1
  const int ofp = (OUT_MODE == 2) ? flags[fo] : 0;

  // Banded XCD swizzle (bijective for nwg%8==0).
  int id = blockIdx.x;
  const int nwg = gridDim.x;
  int swz = id;
  if ((nwg & 7) == 0) swz = (id & 7) * (nwg >> 3) + (id >> 3);
  const int band = gxTiles << 2;
  const int by = (swz & 3) + ((swz / band) << 2);
  const int bx = (swz >> 2) % gxTiles;
  const int m0 = by << 7;
  const int n0 = bx << 7;
  const int NT = K >> 6;

  const int kperm = ((l7 ^ l3) << 3);
  const unsigned short* aSrc[4];
  const unsigned short* bSrc[4];
#pragma unroll
  for (int c = 0; c < 4; ++c) {
    aSrc[c] = A + (long long)(m0 + wave * 32 + c * 8 + l3) * lda + kperm;
    int bn = n0 + wave * 32 + c * 8 + l3;
    if (bn > N - 1) bn = N - 1;  // edge tiles read a valid row
    bSrc[c] = B + (long long)bn * ldb + kperm;
  }

  float4_t acc[4][4];
#pragma unroll
  for (int i = 0; i < 4; ++i)
#pragma unroll
    for (int j = 0; j < 4; ++j) acc[i][j] = (float4_t){0.f, 0.f, 0.f, 0.f};

#pragma unroll
  for (int c = 0; c < 4; ++c) {
    GLDS(aSrc[c], &As2[(wave * 32 + c * 8) * 64]);
    GLDS(bSrc[c], &Bs2[(wave * 32 + c * 8) * 64]);
  }
  asm volatile("s_waitcnt vmcnt(0)" ::: "memory");
  __builtin_amdgcn_s_barrier();

  short8_t af[4], bfr[4];
  for (int tt = 0; tt < NT; ++tt) {
    const int rb = tt & 1, nb = rb ^ 1;
#pragma unroll
    for (int i = 0; i < 4; ++i) af[i] = LDA2(rb, i, 0);
#pragma unroll
    for (int j = 0; j < 4; ++j) bfr[j] = LDB2(rb, j, 0);
    if (tt + 1 < NT) {
      const long long ko = (long long)(tt + 1) << 6;
#pragma unroll
      for (int c = 0; c < 4; ++c) {
        GLDS(aSrc[c] + ko, &As2[nb * 8192 + (wave * 32 + c * 8) * 64]);
        GLDS(bSrc[c] + ko, &Bs2[nb * 8192 + (wave * 32 + c * 8) * 64]);
      }
    }
    __builtin_amdgcn_s_setprio(1);
#pragma unroll
    for (int i = 0; i < 4; ++i)
#pragma unroll
      for (int j = 0; j < 4; ++j) MFMA_ACC(acc[i][j], af[i], bfr[j]);
    __builtin_amdgcn_s_setprio(0);
#pragma unroll
    for (int i = 0; i < 4; ++i) af[i] = LDA2(rb, i, 1);
#pragma unroll
    for (int j = 0; j < 4; ++j) bfr[j] = LDB2(rb, j, 1);
    __builtin_amdgcn_s_setprio(1);
#pragma unroll
    for (int i = 0; i < 4; ++i)
#pragma unroll
      for (int j = 0; j < 4; ++j) MFMA_ACC(acc[i][j], af[i], bfr[j]);
    __builtin_amdgcn_s_setprio(0);
    asm volatile("s_waitcnt vmcnt(0)" ::: "memory");
    __builtin_amdgcn_s_barrier();
  }

#pragma unroll
  for (int i = 0; i < 4; ++i) {
#pragma unroll
    for (int r = 0; r < 4; ++r) {
      const int m = m0 + wm * 64 + i * 16 + quad * 4 + r;
      const long long cb = (long long)m * ldc;
#pragma unroll
      for (int j = 0; j < 4; ++j) {
        const int n = n0 + wn * 64 + j * 16 + l16;
        if (n < N) {
          float v = acc[i][j][r];
          if (ofp) ((float*)Cptr)[cb + n] = v;
          else     ((unsigned short*)Cptr)[cb + n] = f2bf(v);
        }
      }
    }
  }
}

// ---------------------------------------------------------------------------
// MFMA G kernel: G[z][l][s] = sum_n C[z,l][n] * B[z,s][n]. Both operands
// bf16 straight from convx (NO new quantization; fp32 accumulate).
// Grid (2,2,16), 256 thr / 4 waves; each wave 64x64 of the 128x128 tile.
// Direct-global fragments (no LDS) - tiny K=128 GEMM, L2-resident.
// ---------------------------------------------------------------------------
__global__ __launch_bounds__(256)
void gemm_g_k(const unsigned short* __restrict__ convx,
              float* __restrict__ Gm) {
  const int t = threadIdx.x;
  const int lane = t & 63;
  const int wave = t >> 6;
  const int quad = lane >> 4;
  const int l16 = lane & 15;
  const int wm = wave >> 1, wn = wave & 1;
  const int m0 = blockIdx.y * 128 + wm * 64;
  const int n0 = blockIdx.x * 128 + wn * 64;
  const long long row0 = (long long)blockIdx.z * 256;

  float4_t acc[4][4];
#pragma unroll
  for (int i = 0; i < 4; ++i)
#pragma unroll
    for (int j = 0; j < 4; ++j) acc[i][j] = (float4_t){0.f, 0.f, 0.f, 0.f};

#pragma unroll
  for (int kt = 0; kt < 4; ++kt) {
    const int ko = kt * 32 + quad * 8;
    short8_t a[4], b[4];
#pragma unroll
    for (int i = 0; i < 4; ++i)
      a[i] = *(const short8_t*)&convx[(row0 + m0 + i * 16 + l16) * CONV_SZ + COFF + ko];
#pragma unroll
    for (int j = 0; j < 4; ++j)
      b[j] = *(const short8_t*)&convx[(row0 + n0 + j * 16 + l16) * CONV_SZ + BOFF + ko];
#pragma unroll
    for (int i = 0; i < 4; ++i)
#pragma unroll
      for (int j = 0; j < 4; ++j) MFMA_ACC(acc[i][j], a[i], b[j]);
  }
  float* Gb = Gm + (long long)blockIdx.z * 65536;
#pragma unroll
  for (int i = 0; i < 4; ++i)
#pragma unroll
    for (int r = 0; r < 4; ++r) {
      const int m = m0 + i * 16 + quad * 4 + r;
#pragma unroll
      for (int j = 0; j < 4; ++j)
        Gb[(long long)m * 256 + n0 + j * 16 + l16] = acc[i][j][r];
    }
}

// ---------------------------------------------------------------------------
// Depthwise causal conv (K=4) + bias + SiLU over xBC columns of proj.
// ---------------------------------------------------------------------------
__global__ __launch_bounds__(256)
void conv_silu_k(const unsigned short* __restrict__ proj,
                 const void* __restrict__ cw,
                 const void* __restrict__ cb,
                 unsigned short* __restrict__ convx,
                 const int* __restrict__ flags) {
  const int total = B_SZ * L_SZ * (CONV_SZ / 4);
  int g = blockIdx.x * 256 + threadIdx.x;
  if (g >= total) return;
  const int fw = flags[2], fb = flags[3];
  int c4 = g % (CONV_SZ / 4);
  int bl = g / (CONV_SZ / 4);
  int l = bl & (L_SZ - 1);
  int ch = c4 * 4;
  float w0[8], w1[8];
  load8(cw, (long long)ch * 4, fw, w0);
  load8(cw, (long long)ch * 4 + 8, fw, w1);
  float accv[4];
  load4(cb, ch, fb, accv);
  float acc0 = accv[0], acc1 = accv[1], acc2 = accv[2], acc3 = accv[3];
  const long long rb = (long long)(bl - l);
#pragma unroll
  for (int k = 0; k < 4; k++) {
    int ls = l - 3 + k;
    if (ls < 0) continue;
    uint2 xv = *(const uint2*)(proj + (rb + ls) * PROJ_SZ + XOFF + ch);
    float x0 = bf2f((unsigned short)(xv.x & 0xffffu));
    float x1 = bf2f((unsigned short)(xv.x >> 16));
    float x2 = bf2f((unsigned short)(xv.y & 0xffffu));
    float x3 = bf2f((unsigned short)(xv.y >> 16));
    acc0 = fmaf(x0, w0[k], acc0);
    acc1 = fmaf(x1, w0[4 + k], acc1);
    acc2 = fmaf(x2, w1[k], acc2);
    acc3 = fmaf(x3, w1[4 + k], acc3);
  }
  unsigned short o0 = f2bf(silu_f(acc0));
  unsigned short o1 = f2bf(silu_f(acc1));
  unsigned short o2 = f2bf(silu_f(acc2));
  unsigned short o3 = f2bf(silu_f(acc3));
  *(uint2*)(convx + (long long)bl * CONV_SZ + ch) =
      make_uint2((unsigned int)o0 | ((unsigned int)o1 << 16),
                 (unsigned int)o2 | ((unsigned int)o3 << 16));
}

// ---------------------------------------------------------------------------
__global__ __launch_bounds__(256)
void dt_prep_k(const unsigned short* __restrict__ proj,
               const void* __restrict__ dt_bias,
               float* __restrict__ dtv, const int* __restrict__ flags) {
  int g = blockIdx.x * 256 + threadIdx.x;
  int h = g & 63;
  long long bl = g >> 6;
  float v = bf2f(proj[bl * PROJ_SZ + DTOFF + h]) + load1(dt_bias, h, flags[4]);
  float sp = (v > 20.f) ? v : log1pf(expf(v));
  dtv[g] = sp;
}

// ---------------------------------------------------------------------------
__global__ __launch_bounds__(256)
void acs_scan_k(const float* __restrict__ dtv,
                const void* __restrict__ A_log,
                float* __restrict__ acs, const int* __restrict__ flags) {
  __shared__ float sd[256];
  int blk = blockIdx.x;
  int h = blk & 63;
  int bc = blk >> 6;
  int l = threadIdx.x;
  float Ah = -expf(load1(A_log, h, flags[5]));
  long long row = (long long)bc * CH_SZ + l;
  sd[l] = Ah * dtv[row * NH_SZ + h];
  for (int off = 1; off < 256; off <<= 1) {
    __syncthreads();
    float tv = (l >= off) ? sd[l - off] : 0.f;
    __syncthreads();
    sd[l] += tv;
  }
  acs[(long long)blk * CH_SZ + l] = sd[l];
}

// ---------------------------------------------------------------------------
__global__ __launch_bounds__(256)
void chunk_states_k(const unsigned short* __restrict__ convx,
                    const float* __restrict__ dtv,
                    const float* __restrict__ acs,
                    float* __restrict__ stc) {
  __shared__ float Bw[32][128];
  __shared__ float xw[32][64];
  int blk = blockIdx.x;
  int h = blk & 63;
  int bc = blk >> 6;
  int t = threadIdx.x;
  const int p0 = (t & 15) * 4, n0 = (t >> 4) * 8;
  const float* acsb = acs + (long long)blk * 256;
  const float alast = acsb[255];
  float acc[4][8];
#pragma unroll
  for (int i = 0; i < 4; i++)
#pragma unroll
    for (int j = 0; j < 8; j++) acc[i][j] = 0.f;
  const long long row0 = (long long)bc * 256;

  for (int lt0 = 0; lt0 < 256; lt0 += 32) {
    __syncthreads();
#pragma unroll
    for (int q = 0; q < 4; q++) {
      int idx4 = (t + 256 * q) * 4;
      int r = idx4 >> 7, n = idx4 & 127;
      uint2 v = *(const uint2*)(convx + (row0 + lt0 + r) * CONV_SZ + BOFF + n);
      Bw[r][n]     = bf2f((unsigned short)(v.x & 0xffffu));
      Bw[r][n + 1] = bf2f((unsigned short)(v.x >> 16));
      Bw[r][n + 2] = bf2f((unsigned short)(v.y & 0xffffu));
      Bw[r][n + 3] = bf2f((unsigned short)(v.y >> 16));
    }
#pragma unroll
    for (int q = 0; q < 2; q++) {
      int idx4 = (t + 256 * q) * 4;
      int r = idx4 >> 6, p = idx4 & 63;
      long long lg = row0 + lt0 + r;
      float sc = dtv[lg * NH_SZ + h] * expf(alast - acsb[lt0 + r]);
      uint2 v = *(const uint2*)(convx + lg * CONV_SZ + h * 64 + p);
      xw[r][p]     = bf2f((unsigned short)(v.x & 0xffffu)) * sc;
      xw[r][p + 1] = bf2f((unsigned short)(v.x >> 16)) * sc;
      xw[r][p + 2] = bf2f((unsigned short)(v.y & 0xffffu)) * sc;
      xw[r][p + 3] = bf2f((unsigned short)(v.y >> 16)) * sc;
    }
    __syncthreads();
#pragma unroll 4
    for (int lt = 0; lt < 32; lt++) {
      float4 xv = *(const float4*)&xw[lt][p0];
      float4 b0 = *(const float4*)&Bw[lt][n0];
      float4 b1 = *(const float4*)&Bw[lt][n0 + 4];
      float xa[4] = {xv.x, xv.y, xv.z, xv.w};
      float ba[8] = {b0.x, b0.y, b0.z, b0.w, b1.x, b1.y, b1.z, b1.w};
#pragma unroll
      for (int i = 0; i < 4; i++)
#pragma unroll
        for (int j = 0; j < 8; j++) acc[i][j] = fmaf(xa[i], ba[j], acc[i][j]);
    }
  }
  float* outb = stc + (long long)blk * 8192;
#pragma unroll
  for (int i = 0; i < 4; i++) {
    *(float4*)&outb[(p0 + i) * 128 + n0] =
        make_float4(acc[i][0], acc[i][1], acc[i][2], acc[i][3]);
    *(float4*)&outb[(p0 + i) * 128 + n0 + 4] =
        make_float4(acc[i][4], acc[i][5], acc[i][6], acc[i][7]);
  }
}

// ---------------------------------------------------------------------------
__global__ __launch_bounds__(256)
void recur_k(float* __restrict__ stc, const float* __restrict__ acs) {
  int blk = blockIdx.x;
  int b = blk >> 6, h = blk & 63;
  int t = threadIdx.x;
  float S[32];
#pragma unroll
  for (int j = 0; j < 32; j++) S[j] = 0.f;
  for (int z = 0; z < 8; z++) {
    long long bz = ((long long)b * 8 + z) * 64 + h;
    long long base = bz * 8192;
    float e = expf(acs[bz * 256 + 255]);
#pragma unroll
    for (int j = 0; j < 32; j++) {
      int idx = j * 256 + t;
      float cs = stc[base + idx];
      stc[base + idx] = S[j];
      S[j] = fmaf(e, S[j], cs);
    }
  }
}

// ---------------------------------------------------------------------------
// MFMA Y_off: Y_off[l][p] = sum_n C[l][n] * st[p][n]; y = exp(acs)*Y_off
// + D*x. A = C (bf16, convx direct); B = states (fp32 stc -> bf16 in-reg,
// the only new quantization). No LDS; direct-global fragments. 1024 blocks
// (b,c,h), 4 waves each covering 64 l-rows x 64 p-cols, K=128.
// ---------------------------------------------------------------------------
__global__ __launch_bounds__(256)
void yoff_mfma_k(const unsigned short* __restrict__ convx,
                 const float* __restrict__ sti,
                 const float* __restrict__ acs,
                 const void* __restrict__ Dw,
                 float* __restrict__ y, const int* __restrict__ flags) {
  const int blk = blockIdx.x;
  const int h = blk & 63;
  const int bc = blk >> 6;
  const int t = threadIdx.x;
  const int lane = t & 63;
  const int wave = t >> 6;
  const int quad = lane >> 4;
  const int l16 = lane & 15;
  const int l0 = wave * 64;              // wave's l-range base within 256
  const long long row0 = (long long)bc * 256;
  const float* sib = sti + (long long)blk * 8192;   // [p][n]
  const float* acsb = acs + (long long)blk * 256;
  const float Dh = load1(Dw, h, flags[6]);

  float4_t acc[4][4];
#pragma unroll
  for (int i = 0; i < 4; ++i)
#pragma unroll
    for (int j = 0; j < 4; ++j) acc[i][j] = (float4_t){0.f, 0.f, 0.f, 0.f};

#pragma unroll
  for (int kt = 0; kt < 4; ++kt) {
    const int ko = kt * 32 + quad * 8;
    short8_t a[4], b[4];
#pragma unroll
    for (int i = 0; i < 4; ++i)
      a[i] = *(const short8_t*)&convx[(row0 + l0 + i * 16 + l16) * CONV_SZ + COFF + ko];
#pragma unroll
    for (int j = 0; j < 4; ++j)
      b[j] = pack_bf8(sib + (j * 16 + l16) * 128 + ko);
#pragma unroll
    for (int i = 0; i < 4; ++i)
#pragma unroll
      for (int j = 0; j < 4; ++j) MFMA_ACC(acc[i][j], a[i], b[j]);
  }

  // Epilogue: y[row][h*64 + p] = exp(acs[l])*acc + D*x.
#pragma unroll
  for (int i = 0; i < 4; ++i) {
#pragma unroll
    for (int r = 0; r < 4; ++r) {
      const int m = l0 + i * 16 + quad * 4 + r;      // l within chunk
      const long long row = row0 + m;
      const float ex = expf(acsb[m]);
      const unsigned short* xr = convx + row * CONV_SZ + h * 64;
      float* yr = y + row * I_SZ + h * 64;
#pragma unroll
      for (int j = 0; j < 4; ++j) {
        const int p = j * 16 + l16;
        yr[p] = fmaf(ex, acc[i][j][r], Dh * bf2f(xr[p]));
      }
    }
  }
}

// ---------------------------------------------------------------------------
__global__ __launch_bounds__(256)
void ydiag_k(const unsigned short* __restrict__ convx,
             const float* __restrict__ dtv,
             const float* __restrict__ acs,
             const float* __restrict__ Gmat,
             float* __restrict__ y) {
  __shared__ float acs_s[256];
  __shared__ float xsT[64][68];
  __shared__ float Mt[64][66];
  int blk = blockIdx.x;
  int h = blk & 63;
  int bc = blk >> 6;
  int t = threadIdx.x;
  const int txp = t & 15, lq = t >> 4;
  acs_s[t] = acs[(long long)blk * 256 + t];
  const long long row0 = (long long)bc * 256;
  const float* Gb = Gmat + (long long)bc * 65536;
  for (int ltile = 0; ltile < 4; ltile++) {
    float acc[4][4] = {};
    for (int stile = 0; stile <= ltile; stile++) {
      __syncthreads();
#pragma unroll 4
      for (int q = 0; q < 16; q++) {
        int idx = t + 256 * q;
        int ss = idx >> 6, p = idx & 63;
        long long row = row0 + stile * 64 + ss;
        xsT[ss][p] = bf2f(convx[row * CONV_SZ + h * 64 + p]) * dtv[row * NH_SZ + h];
      }
#pragma unroll 4
      for (int q = 0; q < 16; q++) {
        int idx = t + 256 * q;
        int lr = idx >> 6, ss = idx & 63;
        int lg = ltile * 64 + lr, sg = stile * 64 + ss;
        float m = 0.f;
        if (sg <= lg) m = Gb[(long long)lg * 256 + sg] * expf(acs_s[lg] - acs_s[sg]);
        Mt[lr][ss] = m;
      }
      __syncthreads();
#pragma unroll 4
      for (int ss = 0; ss < 64; ss++) {
        float4 xv = *(const float4*)&xsT[ss][txp * 4];
        float m0 = Mt[lq * 4 + 0][ss];
        float m1 = Mt[lq * 4 + 1][ss];
        float m2 = Mt[lq * 4 + 2][ss];
        float m3 = Mt[lq * 4 + 3][ss];
        acc[0][0] = fmaf(m0, xv.x, acc[0][0]); acc[0][1] = fmaf(m0, xv.y, acc[0][1]);
        acc[0][2] = fmaf(m0, xv.z, acc[0][2]); acc[0][3] = fmaf(m0, xv.w, acc[0][3]);
        acc[1][0] = fmaf(m1, xv.x, acc[1][0]); acc[1][1] = fmaf(m1, xv.y, acc[1][1]);
        acc[1][2] = fmaf(m1, xv.z, acc[1][2]); acc[1][3] = fmaf(m1, xv.w, acc[1][3]);
        acc[2][0] = fmaf(m2, xv.x, acc[2][0]); acc[2][1] = fmaf(m2, xv.y, acc[2][1]);
        acc[2][2] = fmaf(m2, xv.z, acc[2][2]); acc[2][3] = fmaf(m2, xv.w, acc[2][3]);
        acc[3][0] = fmaf(m3, xv.x, acc[3][0]); acc[3][1] = fmaf(m3, xv.y, acc[3][1]);
        acc[3][2] = fmaf(m3, xv.z, acc[3][2]); acc[3][3] = fmaf(m3, xv.w, acc[3][3]);
      }
    }
#pragma unroll
    for (int i = 0; i < 4; i++) {
      long long row = row0 + ltile * 64 + lq * 4 + i;
      float* yp = &y[row * I_SZ + h * 64 + txp * 4];
      float4 cur = *(float4*)yp;
      cur.x += acc[i][0]; cur.y += acc[i][1]; cur.z += acc[i][2]; cur.w += acc[i][3];
      *(float4*)yp = cur;
    }
  }
}

// ---------------------------------------------------------------------------
__global__ __launch_bounds__(256)
void norm_k(const float* __restrict__ y,
            const unsigned short* __restrict__ proj,
            const void* __restrict__ nw,
            unsigned short* __restrict__ yfb, const int* __restrict__ flags) {
  __shared__ float red[4];
  __shared__ float sc_s;
  int row = blockIdx.x;
  int t = threadIdx.x;
  const int fn = flags[7];
  const float* yr = y + (long long)row * I_SZ;
  const unsigned short* zr = proj + (long long)row * PROJ_SZ;
  float g[16];
  float ss = 0.f;
#pragma unroll
  for (int q = 0; q < 4; q++) {
    int i0 = q * 1024 + t * 4;
    float4 yv = *(const float4*)&yr[i0];
    uint2 zv = *(const uint2*)&zr[i0];
    float z0 = bf2f((unsigned short)(zv.x & 0xffffu));
    float z1 = bf2f((unsigned short)(zv.x >> 16));
    float z2 = bf2f((unsigned short)(zv.y & 0xffffu));
    float z3 = bf2f((unsigned short)(zv.y >> 16));
    float g0 = yv.x * silu_f(z0), g1 = yv.y * silu_f(z1);
    float g2 = yv.z * silu_f(z2), g3 = yv.w * silu_f(z3);
    g[q * 4 + 0] = g0; g[q * 4 + 1] = g1; g[q * 4 + 2] = g2; g[q * 4 + 3] = g3;
    ss += g0 * g0 + g1 * g1 + g2 * g2 + g3 * g3;
  }
#pragma unroll
  for (int off = 32; off > 0; off >>= 1) ss += __shfl_down(ss, off, 64);
  if ((t & 63) == 0) red[t >> 6] = ss;
  __syncthreads();
  if (t == 0) sc_s = rsqrtf((red[0] + red[1] + red[2] + red[3]) * (1.f / 4096.f) + 1e-5f);
  __syncthreads();
  float sc = sc_s;
#pragma unroll
  for (int q = 0; q < 4; q++) {
    int i0 = q * 1024 + t * 4;
    float nv[4];
    load4(nw, i0, fn, nv);
    unsigned short o0 = f2bf(g[q * 4 + 0] * sc * nv[0]);
    unsigned short o1 = f2bf(g[q * 4 + 1] * sc * nv[1]);
    unsigned short o2 = f2bf(g[q * 4 + 2] * sc * nv[2]);
    unsigned short o3 = f2bf(g[q * 4 + 3] * sc * nv[3]);
    *(uint2*)&yfb[(long long)row * I_SZ + i0] =
        make_uint2((unsigned int)o0 | ((unsigned int)o1 << 16),
                   (unsigned int)o2 | ((unsigned int)o3 << 16));
  }
}

// ---------------------------------------------------------------------------
extern "C" void kernel_launch(void* const* d_in, const int* in_sizes, int n_in,
                              void* d_out, int out_size, void* d_ws, size_t ws_size,
                              hipStream_t stream) {
  const void* hs     = d_in[0];
  const void* W_in   = d_in[1];
  const void* conv_w = d_in[2];
  const void* conv_b = d_in[3];
  const void* dt_b   = d_in[4];
  const void* A_log  = d_in[5];
  const void* Dw     = d_in[6];
  const void* nw     = d_in[7];
  const void* W_out  = d_in[8];

  char* ws = (char*)d_ws;
  size_t off = 0;
  auto alloc = [&](size_t bytes) -> void* {
    void* p = ws + off;
    off += (bytes + 255) & ~(size_t)255;
    return p;
  };
  const long long ML = (long long)B_SZ * L_SZ;  // 4096 rows
  int* flags = (int*)alloc(64);
  unsigned short* proj  = (unsigned short*)alloc(ML * PROJ_SZ * 2);             // 66.5 MB
  unsigned short* convx = (unsigned short*)alloc(ML * CONV_SZ * 2);             // 34 MB
  float* dtv  = (float*)alloc(ML * NH_SZ * 4);                                  // 1 MB
  float* acsb = (float*)alloc((long long)B_SZ * NC_SZ * NH_SZ * CH_SZ * 4);     // 1 MB
  float* Gm   = (float*)alloc((long long)B_SZ * NC_SZ * CH_SZ * CH_SZ * 4);     // 4 MB
  float* stc  = (float*)alloc((long long)B_SZ * NC_SZ * NH_SZ * P_SZ * N_SZ * 4);  // 32 MB
  float* yb   = (float*)alloc(ML * I_SZ * 4);                                   // 64 MB
  unsigned short* yfb = (unsigned short*)stc;  // alias: stc dead after yoff
  // bf16 staging copies alias the yb region (dead until yoff / after norm_k)
  unsigned short* hs_bf   = (unsigned short*)yb;                 // 16 MB
  unsigned short* Win_bf  = (unsigned short*)yb + 8388608;       // 34.9 MB (ends <51MB)
  unsigned short* Wout_bf = (unsigned short*)yb;                 // 16 MB (after norm_k)
  (void)n_in; (void)out_size;
  if (off > ws_size) return;

  dim3 blk(256);
  // 0. per-tensor dtype detection
  detect_k<<<1, blk, 0, stream>>>(hs, W_in, conv_w, conv_b, dt_b, A_log, Dw, nw, W_out,
                                  in_sizes[0], in_sizes[1], in_sizes[2], in_sizes[3],
                                  in_sizes[4], in_sizes[5], in_sizes[6], in_sizes[7],
                                  in_sizes[8], flags);
  // 0a. convert hs, W_in to packed bf16
  cvt_bf16_k<<<dim3(4096), blk, 0, stream>>>(hs, hs_bf, 1048576LL, flags, 0);
  cvt_bf16_k<<<dim3(8512), blk, 0, stream>>>(W_in, Win_bf, 2179072LL, flags, 1);
  // 1. in-proj: proj[4096,8512] = hs @ W_in^T  (bf16 out)
  //    cols 0..8191 via 256^2 8-phase (512 blocks = exactly 2 rounds @ 1/CU)
  gemm_8ph_k<<<dim3(512), dim3(512), 0, stream>>>(
      hs_bf, Win_bf, proj, PROJ_SZ, H_SZ, H_SZ, H_SZ, PROJ_SZ, /*gxTiles=*/32);
  //    cols 8192..8511 (320 cols) via 2ph (grid 32x3 = 96 blocks, 2/CU)
  gemm_2ph_k<0><<<dim3(96), blk, 0, stream>>>(
      hs_bf, Win_bf + 8192LL * 2048, proj + 8192, 320, H_SZ,
      H_SZ, H_SZ, PROJ_SZ, /*gxTiles=*/3, flags, 15);
  // 2. conv + silu
  conv_silu_k<<<dim3((B_SZ * L_SZ * (CONV_SZ / 4) + 255) / 256), blk, 0, stream>>>(
      proj, conv_w, conv_b, convx, flags);
  // 3. dt
  dt_prep_k<<<dim3((unsigned)(ML * NH_SZ / 256)), blk, 0, stream>>>(proj, dt_b, dtv, flags);
  // 4. cumsum A*dt
  acs_scan_k<<<dim3(B_SZ * NC_SZ * NH_SZ), blk, 0, stream>>>(dtv, A_log, acsb, flags);
  // 5. G = Cc @ Bc^T per (b,chunk)  (MFMA, both operands bf16 convx: exact)
  gemm_g_k<<<dim3(2, 2, 16), blk, 0, stream>>>(convx, Gm);
  // 6. per-chunk states
  chunk_states_k<<<dim3(1024), blk, 0, stream>>>(convx, dtv, acsb, stc);
  // 7. inter-chunk recurrence (in-place on stc)
  recur_k<<<dim3(B_SZ * NH_SZ), blk, 0, stream>>>(stc, acsb);
  // 8. Y_off + D*x  (MFMA; overwrites yb; hs_bf/Win_bf dead)
  yoff_mfma_k<<<dim3(1024), blk, 0, stream>>>(convx, stc, acsb, Dw, yb, flags);
  // 9. Y_diag
  ydiag_k<<<dim3(1024), blk, 0, stream>>>(convx, dtv, acsb, Gm, yb);
  // 10. gated RMSNorm
  norm_k<<<dim3((unsigned)ML), blk, 0, stream>>>(yb, proj, nw, yfb, flags);
  // 10a. convert W_out (yb now dead)
  cvt_bf16_k<<<dim3(4096), blk, 0, stream>>>(W_out, Wout_bf, 1048576LL, flags, 8);
  // 11. out-proj: out = yf @ W_out^T, grid 32x16 = 512 blocks = 1 round of
  //     2 blocks/CU. Output dtype follows hs flag.
  gemm_2ph_k<2><<<dim3(512), blk, 0, stream>>>(
      yfb, Wout_bf, d_out, H_SZ, I_SZ, I_SZ, I_SZ, H_SZ, /*gxTiles=*/16,
      flags, 0);
}

// Round 8
// 663.307 us; speedup vs baseline: 1.2057x; 1.0219x over previous
//
#include <hip/hip_runtime.h>
#include <hip/hip_bf16.h>
#include <math.h>

// ---------------------------------------------------------------------------
// Mamba2 mixer forward, MI355X. Round 14: MFMA-ize ydiag.
// R13: 678us, absmax unchanged (bf16 states quantization invisible) ->
// middle-GEMM MFMA conversion validated. This round: ydiag (~110us VALU,
// 4.3 GFLOP) -> ydiag_mfma_k:
//  - xs^T staged ONCE to LDS bf16 [p=64][s=256] stride 264 (one barrier);
//    write conflicts one-time, b128 reads 2-way (free), 16B aligned.
//  - per-wave triangular K-loop (wave w: s-tiles 0..2w+1, no cross-wave sync)
//  - A = M[l][s] = G * exp2((acs_l-acs_s)*log2e), masked, computed in-reg,
//    bf16 pack (only new quantization; same class as R13 states).
//  - B = xsT ds_read b128; 16 MFMA/k-step; y RMW epilogue unchanged.
// LDS ~35KB -> 4 blocks/CU. chunk_states (2 transposes) deferred.
// ---------------------------------------------------------------------------

#define B_SZ 2
#define L_SZ 2048
#define H_SZ 2048
#define I_SZ 4096
#define N_SZ 128
#define NH_SZ 64
#define P_SZ 64
#define CH_SZ 256
#define NC_SZ 8
#define PROJ_SZ 8512
#define CONV_SZ 4352
#define XOFF 4096   // xBC start inside proj row
#define DTOFF 8448  // dt start inside proj row
#define BOFF 4096   // B start inside convx row
#define COFF 4224   // C start inside convx row

typedef __attribute__((ext_vector_type(8))) short short8_t;   // 8 bf16 frag
typedef __attribute__((ext_vector_type(4))) float float4_t;   // MFMA acc

// Direct-to-LDS DMA, 16 B per lane, wave-uniform LDS base.
#define GLDS(gp, lp)                                                   \
  __builtin_amdgcn_global_load_lds(                                    \
      (const __attribute__((address_space(1))) void*)(gp),             \
      (__attribute__((address_space(3))) void*)(lp), 16, 0, 0)

__device__ __forceinline__ float bf2f(unsigned short u) {
  union { unsigned int i; float f; } v; v.i = ((unsigned int)u) << 16; return v.f;
}
__device__ __forceinline__ unsigned short f2bf(float f) {
  union { float f; unsigned int i; } v; v.f = f;
  unsigned int b = v.i + 0x7fffu + ((v.i >> 16) & 1u);
  return (unsigned short)(b >> 16);
}
__device__ __forceinline__ void unpack8(uint4 v, float* f) {
  f[0] = bf2f((unsigned short)(v.x & 0xffffu)); f[1] = bf2f((unsigned short)(v.x >> 16));
  f[2] = bf2f((unsigned short)(v.y & 0xffffu)); f[3] = bf2f((unsigned short)(v.y >> 16));
  f[4] = bf2f((unsigned short)(v.z & 0xffffu)); f[5] = bf2f((unsigned short)(v.z >> 16));
  f[6] = bf2f((unsigned short)(v.w & 0xffffu)); f[7] = bf2f((unsigned short)(v.w >> 16));
}
__device__ __forceinline__ float silu_f(float x) { return x / (1.f + expf(-x)); }

__device__ __forceinline__ float load1(const void* p, long long e, int fp32) {
  return fp32 ? ((const float*)p)[e] : bf2f(((const unsigned short*)p)[e]);
}
__device__ __forceinline__ void load4(const void* p, long long e, int fp32, float* f) {
  if (fp32) {
    float4 a = *(const float4*)((const float*)p + e);
    f[0] = a.x; f[1] = a.y; f[2] = a.z; f[3] = a.w;
  } else {
    uint2 v = *(const uint2*)((const unsigned short*)p + e);
    f[0] = bf2f((unsigned short)(v.x & 0xffffu)); f[1] = bf2f((unsigned short)(v.x >> 16));
    f[2] = bf2f((unsigned short)(v.y & 0xffffu)); f[3] = bf2f((unsigned short)(v.y >> 16));
  }
}
__device__ __forceinline__ void load8(const void* p, long long e, int fp32, float* f) {
  if (fp32) {
    float4 a = *(const float4*)((const float*)p + e);
    float4 b = *(const float4*)((const float*)p + e + 4);
    f[0] = a.x; f[1] = a.y; f[2] = a.z; f[3] = a.w;
    f[4] = b.x; f[5] = b.y; f[6] = b.z; f[7] = b.w;
  } else {
    uint4 v = *(const uint4*)((const unsigned short*)p + e);
    unpack8(v, f);
  }
}
// fp32x8 -> bf16x8 fragment (in-register conversion for MFMA B operand).
__device__ __forceinline__ short8_t pack_bf8(const float* p) {
  float4 a = *(const float4*)p;
  float4 b = *(const float4*)(p + 4);
  short8_t r;
  r[0] = (short)f2bf(a.x); r[1] = (short)f2bf(a.y);
  r[2] = (short)f2bf(a.z); r[3] = (short)f2bf(a.w);
  r[4] = (short)f2bf(b.x); r[5] = (short)f2bf(b.y);
  r[6] = (short)f2bf(b.z); r[7] = (short)f2bf(b.w);
  return r;
}

// ---------------------------------------------------------------------------
// Per-tensor dtype detector (confirmed working R3/R4).
// ---------------------------------------------------------------------------
__global__ void detect_k(const void* p0, const void* p1, const void* p2,
                         const void* p3, const void* p4, const void* p5,
                         const void* p6, const void* p7, const void* p8,
                         int n0, int n1, int n2, int n3, int n4, int n5,
                         int n6, int n7, int n8, int* flags) {
  __shared__ int pe, po;
  const void* ps[9] = {p0, p1, p2, p3, p4, p5, p6, p7, p8};
  int ns[9] = {n0, n1, n2, n3, n4, n5, n6, n7, n8};
  int t = threadIdx.x;
  for (int i = 0; i < 9; i++) {
    if (t == 0) { pe = 0; po = 0; }
    __syncthreads();
    int S = ns[i] < 256 ? ns[i] : 256;
    if (t < S) {
      unsigned short u = ((const unsigned short*)ps[i])[t];
      int ex = (u >> 7) & 0xFF;
      int plaus = ((u & 0x7FFFu) != 0) && (ex >= 0x70) && (ex <= 0x8F);
      if (plaus) { if (t & 1) atomicAdd(&po, 1); else atomicAdd(&pe, 1); }
    }
    __syncthreads();
    if (t == 0) flags[i] = (2 * pe < po) ? 1 : 0;
    __syncthreads();
  }
  if (t == 0) { flags[14] = 0; flags[15] = 0; }  // internal buffers: bf16
}

// ---------------------------------------------------------------------------
// fp32 (or bf16 passthrough) -> packed bf16. 8 elems/thread. n8 = n/8.
// ---------------------------------------------------------------------------
__global__ __launch_bounds__(256)
void cvt_bf16_k(const void* __restrict__ src, unsigned short* __restrict__ dst,
                long long n8, const int* __restrict__ flags, int fi) {
  long long g = (long long)blockIdx.x * 256 + threadIdx.x;
  if (g >= n8) return;
  long long e = g * 8;
  if (flags[fi]) {
    const float* s = (const float*)src + e;
    float4 a = *(const float4*)s;
    float4 b = *(const float4*)(s + 4);
    unsigned short o[8] = {f2bf(a.x), f2bf(a.y), f2bf(a.z), f2bf(a.w),
                           f2bf(b.x), f2bf(b.y), f2bf(b.z), f2bf(b.w)};
    *(uint4*)(dst + e) = *(const uint4*)o;
  } else {
    *(uint4*)(dst + e) = *(const uint4*)((const unsigned short*)src + e);
  }
}

// ---------------------------------------------------------------------------
// 256x256 8-phase MFMA GEMM (measured 137us on in-proj main).
// ---------------------------------------------------------------------------
#define MFMA_ACC(d, a, b) \
  d = __builtin_amdgcn_mfma_f32_16x16x32_bf16(a, b, d, 0, 0, 0)
#define LDA_FR(buf, i, kk) \
  (*(const short8_t*)&As[(buf)*16384 + (wm*128 + (i)*16 + l16)*64 + \
                         (((((kk)<<2) + quad) ^ l7) << 3)])
#define LDB_FR(buf, j, kk) \
  (*(const short8_t*)&Bs[(buf)*16384 + (wn*64 + (j)*16 + l16)*64 + \
                         (((((kk)<<2) + quad) ^ l7) << 3)])
#define STAGE_A(h, tile, buf) do {                                          \
    GLDS(aSrc[h][0] + ((long long)(tile) << 6),                             \
         &As[(buf)*16384 + (h)*8192 + (wave*16)*64]);                       \
    GLDS(aSrc[h][1] + ((long long)(tile) << 6),                             \
         &As[(buf)*16384 + (h)*8192 + (wave*16 + 8)*64]);                   \
  } while (0)
#define STAGE_B(h, tile, buf) do {                                          \
    GLDS(bSrc[h][0] + ((long long)(tile) << 6),                             \
         &Bs[(buf)*16384 + (h)*8192 + (wave*16)*64]);                       \
    GLDS(bSrc[h][1] + ((long long)(tile) << 6),                             \
         &Bs[(buf)*16384 + (h)*8192 + (wave*16 + 8)*64]);                   \
  } while (0)

__global__ __launch_bounds__(512, 2)
void gemm_8ph_k(const unsigned short* __restrict__ A,
                const unsigned short* __restrict__ B,
                unsigned short* __restrict__ C,
                int N, int K, int lda, int ldb, int ldc, int gxTiles) {
  __shared__ alignas(16) unsigned short As[2 * 256 * 64];
  __shared__ alignas(16) unsigned short Bs[2 * 256 * 64];
  const int t = threadIdx.x;
  const int lane = t & 63;
  const int wave = t >> 6;
  const int quad = lane >> 4;
  const int l16 = lane & 15;
  const int l7 = lane & 7;
  const int l3 = lane >> 3;
  const int wm = wave >> 2;   // 0..1
  const int wn = wave & 3;    // 0..3

  // T1: banded XCD swizzle.
  int id = blockIdx.x;
  const int nwg = gridDim.x;
  int swz = id;
  if ((nwg & 7) == 0) swz = (id & 7) * (nwg >> 3) + (id >> 3);
  const int band = gxTiles << 2;
  const int by = (swz & 3) + ((swz / band) << 2);
  const int bx = (swz >> 2) % gxTiles;
  const int m0 = by << 8;
  const int n0 = bx << 8;
  const int NT = K >> 6;

  const int kperm = ((l7 ^ l3) << 3);
  const unsigned short* aSrc[2][2];
  const unsigned short* bSrc[2][2];
#pragma unroll
  for (int h = 0; h < 2; ++h)
#pragma unroll
    for (int c = 0; c < 2; ++c) {
      const int rloc = h * 128 + wave * 16 + c * 8 + l3;
      aSrc[h][c] = A + (long long)(m0 + rloc) * lda + kperm;
      int bn = n0 + rloc;
      if (bn > N - 1) bn = N - 1;  // clamp: edge tiles read a valid row
      bSrc[h][c] = B + (long long)bn * ldb + kperm;
    }

  float4_t acc[8][4];
#pragma unroll
  for (int i = 0; i < 8; ++i)
#pragma unroll
    for (int j = 0; j < 4; ++j) acc[i][j] = (float4_t){0.f, 0.f, 0.f, 0.f};

  STAGE_A(0, 0, 0); STAGE_A(1, 0, 0);
  STAGE_B(0, 0, 0); STAGE_B(1, 0, 0);
  STAGE_B(0, 1, 1); STAGE_B(1, 1, 1);
  asm volatile("s_waitcnt vmcnt(4)" ::: "memory");  // tile0 landed
  __builtin_amdgcn_s_barrier();

  short8_t af[4][2], bf[4][2];
  for (int tt = 0; tt < NT; ++tt) {
    const int rb = tt & 1, nb = rb ^ 1;
    // ---- phase 1 ----
#pragma unroll
    for (int i = 0; i < 4; ++i) af[i][0] = LDA_FR(rb, i, 0);
#pragma unroll
    for (int j = 0; j < 4; ++j) bf[j][0] = LDB_FR(rb, j, 0);
    if (tt + 1 < NT) STAGE_A(0, tt + 1, nb);
    asm volatile("s_waitcnt lgkmcnt(4)" ::: "memory");
    __builtin_amdgcn_s_barrier();
    asm volatile("s_waitcnt lgkmcnt(0)" ::: "memory");
    __builtin_amdgcn_s_setprio(1);
#pragma unroll
    for (int i = 0; i < 4; ++i)
#pragma unroll
      for (int j = 0; j < 4; ++j) MFMA_ACC(acc[i][j], af[i][0], bf[j][0]);
    __builtin_amdgcn_s_setprio(0);
    __builtin_amdgcn_s_barrier();
    // ---- phase 2 ----
#pragma unroll
    for (int i = 0; i < 4; ++i) af[i][1] = LDA_FR(rb, i, 1);
#pragma unroll
    for (int j = 0; j < 4; ++j) bf[j][1] = LDB_FR(rb, j, 1);
    if (tt + 1 < NT) STAGE_A(1, tt + 1, nb);
    asm volatile("s_waitcnt lgkmcnt(4)" ::: "memory");
    __builtin_amdgcn_s_barrier();
    asm volatile("s_waitcnt lgkmcnt(0)" ::: "memory");
    __builtin_amdgcn_s_setprio(1);
#pragma unroll
    for (int i = 0; i < 4; ++i)
#pragma unroll
      for (int j = 0; j < 4; ++j) MFMA_ACC(acc[i][j], af[i][1], bf[j][1]);
    __builtin_amdgcn_s_setprio(0);
    __builtin_amdgcn_s_barrier();
    // ---- phase 3 ----
#pragma unroll
    for (int i = 0; i < 4; ++i) af[i][0] = LDA_FR(rb, 4 + i, 0);
    if (tt + 2 < NT) STAGE_B(0, tt + 2, rb);
    __builtin_amdgcn_s_barrier();
    asm volatile("s_waitcnt lgkmcnt(0)" ::: "memory");
    __builtin_amdgcn_s_setprio(1);
#pragma unroll
    for (int i = 0; i < 4; ++i)
#pragma unroll
      for (int j = 0; j < 4; ++j) MFMA_ACC(acc[4 + i][j], af[i][0], bf[j][0]);
    __builtin_amdgcn_s_setprio(0);
    __builtin_amdgcn_s_barrier();
    // ---- phase 4 ----
#pragma unroll
    for (int i = 0; i < 4; ++i) af[i][1] = LDA_FR(rb, 4 + i, 1);
    if (tt + 2 < NT) STAGE_B(1, tt + 2, rb);
    __builtin_amdgcn_s_barrier();
    asm volatile("s_waitcnt lgkmcnt(0)" ::: "memory");
    __builtin_amdgcn_s_setprio(1);
#pragma unroll
    for (int i = 0; i < 4; ++i)
#pragma unroll
      for (int j = 0; j < 4; ++j) MFMA_ACC(acc[4 + i][j], af[i][1], bf[j][1]);
    __builtin_amdgcn_s_setprio(0);
    if (tt < NT - 2) asm volatile("s_waitcnt vmcnt(4)" ::: "memory");
    else             asm volatile("s_waitcnt vmcnt(0)" ::: "memory");
    __builtin_amdgcn_s_barrier();
  }

#pragma unroll
  for (int i = 0; i < 8; ++i) {
#pragma unroll
    for (int r = 0; r < 4; ++r) {
      const int m = m0 + wm * 128 + i * 16 + quad * 4 + r;
      const long long cb = (long long)m * ldc;
#pragma unroll
      for (int j = 0; j < 4; ++j) {
        const int n = n0 + wn * 64 + j * 16 + l16;
        if (n < N) C[cb + n] = f2bf(acc[i][j][r]);
      }
    }
  }
}

// ---------------------------------------------------------------------------
// 128x128 2-phase MFMA GEMM, 2 blocks/CU (in-proj tail, out-proj).
// ---------------------------------------------------------------------------
#define LDA2(buf, i, kk) \
  (*(const short8_t*)&As2[(buf)*8192 + (wm*64 + (i)*16 + l16)*64 + \
                          (((((kk)<<2) + quad) ^ l7) << 3)])
#define LDB2(buf, j, kk) \
  (*(const short8_t*)&Bs2[(buf)*8192 + (wn*64 + (j)*16 + l16)*64 + \
                          (((((kk)<<2) + quad) ^ l7) << 3)])

template <int OUT_MODE>
__global__ __launch_bounds__(256, 2)
void gemm_2ph_k(const unsigned short* __restrict__ A,
                const unsigned short* __restrict__ B,
                void* __restrict__ Cptr,
                int N, int K, int lda, int ldb, int ldc, int gxTiles,
                const int* __restrict__ flags, int fo) {
  __shared__ alignas(16) unsigned short As2[2 * 128 * 64];
  __shared__ alignas(16) unsigned short Bs2[2 * 128 * 64];
  const int t = threadIdx.x;
  const int lane = t & 63;
  const int wave = t >> 6;   // 0..3
  const int quad = lane >> 4;
  const int l16 = lane & 15;
  const int l7 = lane & 7;
  const int l3 = lane >> 3;
  const int wm = wave >> 1;  // 0..1
  const int wn = wave & 1;   // 0..1
  const int ofp = (OUT_MODE == 2) ? flags[fo] : 0;

  int id = blockIdx.x;
  const int nwg = gridDim.x;
  int swz = id;
  if ((nwg & 7) == 0) swz = (id & 7) * (nwg >> 3) + (id >> 3);
  const int band = gxTiles << 2;
  const int by = (swz & 3) + ((swz / band) << 2);
  const int bx = (swz >> 2) % gxTiles;
  const int m0 = by << 7;
  const int n0 = bx << 7;
  const int NT = K >> 6;

  const int kperm = ((l7 ^ l3) << 3);
  const unsigned short* aSrc[4];
  const unsigned short* bSrc[4];
#pragma unroll
  for (int c = 0; c < 4; ++c) {
    aSrc[c] = A + (long long)(m0 + wave * 32 + c * 8 + l3) * lda + kperm;
    int bn = n0 + wave * 32 + c * 8 + l3;
    if (bn > N - 1) bn = N - 1;  // edge tiles read a valid row
    bSrc[c] = B + (long long)bn * ldb + kperm;
  }

  float4_t acc[4][4];
#pragma unroll
  for (int i = 0; i < 4; ++i)
#pragma unroll
    for (int j = 0; j < 4; ++j) acc[i][j] = (float4_t){0.f, 0.f, 0.f, 0.f};

#pragma unroll
  for (int c = 0; c < 4; ++c) {
    GLDS(aSrc[c], &As2[(wave * 32 + c * 8) * 64]);
    GLDS(bSrc[c], &Bs2[(wave * 32 + c * 8) * 64]);
  }
  asm volatile("s_waitcnt vmcnt(0)" ::: "memory");
  __builtin_amdgcn_s_barrier();

  short8_t af[4], bfr[4];
  for (int tt = 0; tt < NT; ++tt) {
    const int rb = tt & 1, nb = rb ^ 1;
#pragma unroll
    for (int i = 0; i < 4; ++i) af[i] = LDA2(rb, i, 0);
#pragma unroll
    for (int j = 0; j < 4; ++j) bfr[j] = LDB2(rb, j, 0);
    if (tt + 1 < NT) {
      const long long ko = (long long)(tt + 1) << 6;
#pragma unroll
      for (int c = 0; c < 4; ++c) {
        GLDS(aSrc[c] + ko, &As2[nb * 8192 + (wave * 32 + c * 8) * 64]);
        GLDS(bSrc[c] + ko, &Bs2[nb * 8192 + (wave * 32 + c * 8) * 64]);
      }
    }
    __builtin_amdgcn_s_setprio(1);
#pragma unroll
    for (int i = 0; i < 4; ++i)
#pragma unroll
      for (int j = 0; j < 4; ++j) MFMA_ACC(acc[i][j], af[i], bfr[j]);
    __builtin_amdgcn_s_setprio(0);
#pragma unroll
    for (int i = 0; i < 4; ++i) af[i] = LDA2(rb, i, 1);
#pragma unroll
    for (int j = 0; j < 4; ++j) bfr[j] = LDB2(rb, j, 1);
    __builtin_amdgcn_s_setprio(1);
#pragma unroll
    for (int i = 0; i < 4; ++i)
#pragma unroll
      for (int j = 0; j < 4; ++j) MFMA_ACC(acc[i][j], af[i], bfr[j]);
    __builtin_amdgcn_s_setprio(0);
    asm volatile("s_waitcnt vmcnt(0)" ::: "memory");
    __builtin_amdgcn_s_barrier();
  }

#pragma unroll
  for (int i = 0; i < 4; ++i) {
#pragma unroll
    for (int r = 0; r < 4; ++r) {
      const int m = m0 + wm * 64 + i * 16 + quad * 4 + r;
      const long long cb = (long long)m * ldc;
#pragma unroll
      for (int j = 0; j < 4; ++j) {
        const int n = n0 + wn * 64 + j * 16 + l16;
        if (n < N) {
          float v = acc[i][j][r];
          if (ofp) ((float*)Cptr)[cb + n] = v;
          else     ((unsigned short*)Cptr)[cb + n] = f2bf(v);
        }
      }
    }
  }
}

// ---------------------------------------------------------------------------
// MFMA G kernel: G[z][l][s] = sum_n C[z,l][n] * B[z,s][n]. Exact (bf16 in).
// ---------------------------------------------------------------------------
__global__ __launch_bounds__(256)
void gemm_g_k(const unsigned short* __restrict__ convx,
              float* __restrict__ Gm) {
  const int t = threadIdx.x;
  const int lane = t & 63;
  const int wave = t >> 6;
  const int quad = lane >> 4;
  const int l16 = lane & 15;
  const int wm = wave >> 1, wn = wave & 1;
  const int m0 = blockIdx.y * 128 + wm * 64;
  const int n0 = blockIdx.x * 128 + wn * 64;
  const long long row0 = (long long)blockIdx.z * 256;

  float4_t acc[4][4];
#pragma unroll
  for (int i = 0; i < 4; ++i)
#pragma unroll
    for (int j = 0; j < 4; ++j) acc[i][j] = (float4_t){0.f, 0.f, 0.f, 0.f};

#pragma unroll
  for (int kt = 0; kt < 4; ++kt) {
    const int ko = kt * 32 + quad * 8;
    short8_t a[4], b[4];
#pragma unroll
    for (int i = 0; i < 4; ++i)
      a[i] = *(const short8_t*)&convx[(row0 + m0 + i * 16 + l16) * CONV_SZ + COFF + ko];
#pragma unroll
    for (int j = 0; j < 4; ++j)
      b[j] = *(const short8_t*)&convx[(row0 + n0 + j * 16 + l16) * CONV_SZ + BOFF + ko];
#pragma unroll
    for (int i = 0; i < 4; ++i)
#pragma unroll
      for (int j = 0; j < 4; ++j) MFMA_ACC(acc[i][j], a[i], b[j]);
  }
  float* Gb = Gm + (long long)blockIdx.z * 65536;
#pragma unroll
  for (int i = 0; i < 4; ++i)
#pragma unroll
    for (int r = 0; r < 4; ++r) {
      const int m = m0 + i * 16 + quad * 4 + r;
#pragma unroll
      for (int j = 0; j < 4; ++j)
        Gb[(long long)m * 256 + n0 + j * 16 + l16] = acc[i][j][r];
    }
}

// ---------------------------------------------------------------------------
// Depthwise causal conv (K=4) + bias + SiLU over xBC columns of proj.
// ---------------------------------------------------------------------------
__global__ __launch_bounds__(256)
void conv_silu_k(const unsigned short* __restrict__ proj,
                 const void* __restrict__ cw,
                 const void* __restrict__ cb,
                 unsigned short* __restrict__ convx,
                 const int* __restrict__ flags) {
  const int total = B_SZ * L_SZ * (CONV_SZ / 4);
  int g = blockIdx.x * 256 + threadIdx.x;
  if (g >= total) return;
  const int fw = flags[2], fb = flags[3];
  int c4 = g % (CONV_SZ / 4);
  int bl = g / (CONV_SZ / 4);
  int l = bl & (L_SZ - 1);
  int ch = c4 * 4;
  float w0[8], w1[8];
  load8(cw, (long long)ch * 4, fw, w0);
  load8(cw, (long long)ch * 4 + 8, fw, w1);
  float accv[4];
  load4(cb, ch, fb, accv);
  float acc0 = accv[0], acc1 = accv[1], acc2 = accv[2], acc3 = accv[3];
  const long long rb = (long long)(bl - l);
#pragma unroll
  for (int k = 0; k < 4; k++) {
    int ls = l - 3 + k;
    if (ls < 0) continue;
    uint2 xv = *(const uint2*)(proj + (rb + ls) * PROJ_SZ + XOFF + ch);
    float x0 = bf2f((unsigned short)(xv.x & 0xffffu));
    float x1 = bf2f((unsigned short)(xv.x >> 16));
    float x2 = bf2f((unsigned short)(xv.y & 0xffffu));
    float x3 = bf2f((unsigned short)(xv.y >> 16));
    acc0 = fmaf(x0, w0[k], acc0);
    acc1 = fmaf(x1, w0[4 + k], acc1);
    acc2 = fmaf(x2, w1[k], acc2);
    acc3 = fmaf(x3, w1[4 + k], acc3);
  }
  unsigned short o0 = f2bf(silu_f(acc0));
  unsigned short o1 = f2bf(silu_f(acc1));
  unsigned short o2 = f2bf(silu_f(acc2));
  unsigned short o3 = f2bf(silu_f(acc3));
  *(uint2*)(convx + (long long)bl * CONV_SZ + ch) =
      make_uint2((unsigned int)o0 | ((unsigned int)o1 << 16),
                 (unsigned int)o2 | ((unsigned int)o3 << 16));
}

// ---------------------------------------------------------------------------
__global__ __launch_bounds__(256)
void dt_prep_k(const unsigned short* __restrict__ proj,
               const void* __restrict__ dt_bias,
               float* __restrict__ dtv, const int* __restrict__ flags) {
  int g = blockIdx.x * 256 + threadIdx.x;
  int h = g & 63;
  long long bl = g >> 6;
  float v = bf2f(proj[bl * PROJ_SZ + DTOFF + h]) + load1(dt_bias, h, flags[4]);
  float sp = (v > 20.f) ? v : log1pf(expf(v));
  dtv[g] = sp;
}

// ---------------------------------------------------------------------------
__global__ __launch_bounds__(256)
void acs_scan_k(const float* __restrict__ dtv,
                const void* __restrict__ A_log,
                float* __restrict__ acs, const int* __restrict__ flags) {
  __shared__ float sd[256];
  int blk = blockIdx.x;
  int h = blk & 63;
  int bc = blk >> 6;
  int l = threadIdx.x;
  float Ah = -expf(load1(A_log, h, flags[5]));
  long long row = (long long)bc * CH_SZ + l;
  sd[l] = Ah * dtv[row * NH_SZ + h];
  for (int off = 1; off < 256; off <<= 1) {
    __syncthreads();
    float tv = (l >= off) ? sd[l - off] : 0.f;
    __syncthreads();
    sd[l] += tv;
  }
  acs[(long long)blk * CH_SZ + l] = sd[l];
}

// ---------------------------------------------------------------------------
__global__ __launch_bounds__(256)
void chunk_states_k(const unsigned short* __restrict__ convx,
                    const float* __restrict__ dtv,
                    const float* __restrict__ acs,
                    float* __restrict__ stc) {
  __shared__ float Bw[32][128];
  __shared__ float xw[32][64];
  int blk = blockIdx.x;
  int h = blk & 63;
  int bc = blk >> 6;
  int t = threadIdx.x;
  const int p0 = (t & 15) * 4, n0 = (t >> 4) * 8;
  const float* acsb = acs + (long long)blk * 256;
  const float alast = acsb[255];
  float acc[4][8];
#pragma unroll
  for (int i = 0; i < 4; i++)
#pragma unroll
    for (int j = 0; j < 8; j++) acc[i][j] = 0.f;
  const long long row0 = (long long)bc * 256;

  for (int lt0 = 0; lt0 < 256; lt0 += 32) {
    __syncthreads();
#pragma unroll
    for (int q = 0; q < 4; q++) {
      int idx4 = (t + 256 * q) * 4;
      int r = idx4 >> 7, n = idx4 & 127;
      uint2 v = *(const uint2*)(convx + (row0 + lt0 + r) * CONV_SZ + BOFF + n);
      Bw[r][n]     = bf2f((unsigned short)(v.x & 0xffffu));
      Bw[r][n + 1] = bf2f((unsigned short)(v.x >> 16));
      Bw[r][n + 2] = bf2f((unsigned short)(v.y & 0xffffu));
      Bw[r][n + 3] = bf2f((unsigned short)(v.y >> 16));
    }
#pragma unroll
    for (int q = 0; q < 2; q++) {
      int idx4 = (t + 256 * q) * 4;
      int r = idx4 >> 6, p = idx4 & 63;
      long long lg = row0 + lt0 + r;
      float sc = dtv[lg * NH_SZ + h] * expf(alast - acsb[lt0 + r]);
      uint2 v = *(const uint2*)(convx + lg * CONV_SZ + h * 64 + p);
      xw[r][p]     = bf2f((unsigned short)(v.x & 0xffffu)) * sc;
      xw[r][p + 1] = bf2f((unsigned short)(v.x >> 16)) * sc;
      xw[r][p + 2] = bf2f((unsigned short)(v.y & 0xffffu)) * sc;
      xw[r][p + 3] = bf2f((unsigned short)(v.y >> 16)) * sc;
    }
    __syncthreads();
#pragma unroll 4
    for (int lt = 0; lt < 32; lt++) {
      float4 xv = *(const float4*)&xw[lt][p0];
      float4 b0 = *(const float4*)&Bw[lt][n0];
      float4 b1 = *(const float4*)&Bw[lt][n0 + 4];
      float xa[4] = {xv.x, xv.y, xv.z, xv.w};
      float ba[8] = {b0.x, b0.y, b0.z, b0.w, b1.x, b1.y, b1.z, b1.w};
#pragma unroll
      for (int i = 0; i < 4; i++)
#pragma unroll
        for (int j = 0; j < 8; j++) acc[i][j] = fmaf(xa[i], ba[j], acc[i][j]);
    }
  }
  float* outb = stc + (long long)blk * 8192;
#pragma unroll
  for (int i = 0; i < 4; i++) {
    *(float4*)&outb[(p0 + i) * 128 + n0] =
        make_float4(acc[i][0], acc[i][1], acc[i][2], acc[i][3]);
    *(float4*)&outb[(p0 + i) * 128 + n0 + 4] =
        make_float4(acc[i][4], acc[i][5], acc[i][6], acc[i][7]);
  }
}

// ---------------------------------------------------------------------------
__global__ __launch_bounds__(256)
void recur_k(float* __restrict__ stc, const float* __restrict__ acs) {
  int blk = blockIdx.x;
  int b = blk >> 6, h = blk & 63;
  int t = threadIdx.x;
  float S[32];
#pragma unroll
  for (int j = 0; j < 32; j++) S[j] = 0.f;
  for (int z = 0; z < 8; z++) {
    long long bz = ((long long)b * 8 + z) * 64 + h;
    long long base = bz * 8192;
    float e = expf(acs[bz * 256 + 255]);
#pragma unroll
    for (int j = 0; j < 32; j++) {
      int idx = j * 256 + t;
      float cs = stc[base + idx];
      stc[base + idx] = S[j];
      S[j] = fmaf(e, S[j], cs);
    }
  }
}

// ---------------------------------------------------------------------------
// MFMA Y_off: Y_off[l][p] = sum_n C[l][n] * st[p][n]; y = exp(acs)*Y_off
// + D*x. (R13, measured good.)
// ---------------------------------------------------------------------------
__global__ __launch_bounds__(256)
void yoff_mfma_k(const unsigned short* __restrict__ convx,
                 const float* __restrict__ sti,
                 const float* __restrict__ acs,
                 const void* __restrict__ Dw,
                 float* __restrict__ y, const int* __restrict__ flags) {
  const int blk = blockIdx.x;
  const int h = blk & 63;
  const int bc = blk >> 6;
  const int t = threadIdx.x;
  const int lane = t & 63;
  const int wave = t >> 6;
  const int quad = lane >> 4;
  const int l16 = lane & 15;
  const int l0 = wave * 64;
  const long long row0 = (long long)bc * 256;
  const float* sib = sti + (long long)blk * 8192;   // [p][n]
  const float* acsb = acs + (long long)blk * 256;
  const float Dh = load1(Dw, h, flags[6]);

  float4_t acc[4][4];
#pragma unroll
  for (int i = 0; i < 4; ++i)
#pragma unroll
    for (int j = 0; j < 4; ++j) acc[i][j] = (float4_t){0.f, 0.f, 0.f, 0.f};

#pragma unroll
  for (int kt = 0; kt < 4; ++kt) {
    const int ko = kt * 32 + quad * 8;
    short8_t a[4], b[4];
#pragma unroll
    for (int i = 0; i < 4; ++i)
      a[i] = *(const short8_t*)&convx[(row0 + l0 + i * 16 + l16) * CONV_SZ + COFF + ko];
#pragma unroll
    for (int j = 0; j < 4; ++j)
      b[j] = pack_bf8(sib + (j * 16 + l16) * 128 + ko);
#pragma unroll
    for (int i = 0; i < 4; ++i)
#pragma unroll
      for (int j = 0; j < 4; ++j) MFMA_ACC(acc[i][j], a[i], b[j]);
  }

#pragma unroll
  for (int i = 0; i < 4; ++i) {
#pragma unroll
    for (int r = 0; r < 4; ++r) {
      const int m = l0 + i * 16 + quad * 4 + r;
      const long long row = row0 + m;
      const float ex = expf(acsb[m]);
      const unsigned short* xr = convx + row * CONV_SZ + h * 64;
      float* yr = y + row * I_SZ + h * 64;
#pragma unroll
      for (int j = 0; j < 4; ++j) {
        const int p = j * 16 + l16;
        yr[p] = fmaf(ex, acc[i][j][r], Dh * bf2f(xr[p]));
      }
    }
  }
}

// ---------------------------------------------------------------------------
// MFMA Y_diag: Y_diag[l][p] = sum_{s<=l} M[l][s]*xs[s][p],
// M = G * exp(acs_l - acs_s). xs^T staged ONCE to LDS bf16 [p=64][s=256]
// (stride 264: 16B-aligned rows, read conflicts 2-way=free; staging-write
// 8-way but one-time). One barrier; then each wave runs its triangular
// K-loop independently (wave w: s-tiles 0..2w+1). A = M computed in-reg
// (bf16 pack = only new quantization); exp via exp2f (maps to v_exp).
// LDS ~34KB -> 4 blocks/CU. Epilogue: y += acc (RMW, unchanged semantics).
// ---------------------------------------------------------------------------
__global__ __launch_bounds__(256)
void ydiag_mfma_k(const unsigned short* __restrict__ convx,
                  const float* __restrict__ dtv,
                  const float* __restrict__ acs,
                  const float* __restrict__ Gmat,
                  float* __restrict__ y) {
  __shared__ alignas(16) unsigned short xsT[64 * 264];  // [p][s], stride 264
  __shared__ float acs_s[256];
  const int blk = blockIdx.x;
  const int h = blk & 63;
  const int bc = blk >> 6;
  const int t = threadIdx.x;
  const int lane = t & 63;
  const int wave = t >> 6;
  const int quad = lane >> 4;
  const int l16 = lane & 15;
  const long long row0 = (long long)bc * 256;
  const float* Gb = Gmat + (long long)bc * 65536;

  acs_s[t] = acs[(long long)blk * 256 + t];
  // stage xs^T: xs[s][p] = x[s][p]*dt[s] -> xsT[p][s] (2 s per thread-iter)
#pragma unroll 4
  for (int q = 0; q < 32; ++q) {
    int idx = t + 256 * q;
    int s2 = idx >> 6, p = idx & 63;
    int s = s2 * 2;
    long long r0 = row0 + s;
    float d0 = dtv[r0 * NH_SZ + h];
    float d1 = dtv[(r0 + 1) * NH_SZ + h];
    float v0 = bf2f(convx[r0 * CONV_SZ + h * 64 + p]) * d0;
    float v1 = bf2f(convx[(r0 + 1) * CONV_SZ + h * 64 + p]) * d1;
    *(unsigned int*)&xsT[p * 264 + s] =
        (unsigned int)f2bf(v0) | ((unsigned int)f2bf(v1) << 16);
  }
  __syncthreads();

  float4_t acc[4][4];
#pragma unroll
  for (int i = 0; i < 4; ++i)
#pragma unroll
    for (int j = 0; j < 4; ++j) acc[i][j] = (float4_t){0.f, 0.f, 0.f, 0.f};

  const int l0 = wave * 64;
  const int nst = 2 * wave + 2;        // triangular: s-tiles 0..2w+1
  for (int st = 0; st < nst; ++st) {
    const int sb = st * 32 + quad * 8;
    short8_t a[4], b[4];
#pragma unroll
    for (int i = 0; i < 4; ++i) {
      const int lg = l0 + i * 16 + l16;
      const float al = acs_s[lg];
      const float* gr = Gb + (long long)lg * 256 + sb;
      short8_t m;
#pragma unroll
      for (int e = 0; e < 8; ++e) {
        const int sg = sb + e;
        float v = 0.f;
        if (sg <= lg)
          v = gr[e] * exp2f((al - acs_s[sg]) * 1.4426950408889634f);
        m[e] = (short)f2bf(v);
      }
      a[i] = m;
    }
#pragma unroll
    for (int j = 0; j < 4; ++j)
      b[j] = *(const short8_t*)&xsT[(j * 16 + l16) * 264 + sb];
#pragma unroll
    for (int i = 0; i < 4; ++i)
#pragma unroll
      for (int j = 0; j < 4; ++j) MFMA_ACC(acc[i][j], a[i], b[j]);
  }

  // Epilogue: y += Y_diag (RMW).
#pragma unroll
  for (int i = 0; i < 4; ++i) {
#pragma unroll
    for (int r = 0; r < 4; ++r) {
      const int m = l0 + i * 16 + quad * 4 + r;
      float* yr = y + (row0 + m) * I_SZ + h * 64;
#pragma unroll
      for (int j = 0; j < 4; ++j) {
        const int p = j * 16 + l16;
        yr[p] += acc[i][j][r];
      }
    }
  }
}

// ---------------------------------------------------------------------------
__global__ __launch_bounds__(256)
void norm_k(const float* __restrict__ y,
            const unsigned short* __restrict__ proj,
            const void* __restrict__ nw,
            unsigned short* __restrict__ yfb, const int* __restrict__ flags) {
  __shared__ float red[4];
  __shared__ float sc_s;
  int row = blockIdx.x;
  int t = threadIdx.x;
  const int fn = flags[7];
  const float* yr = y + (long long)row * I_SZ;
  const unsigned short* zr = proj + (long long)row * PROJ_SZ;
  float g[16];
  float ss = 0.f;
#pragma unroll
  for (int q = 0; q < 4; q++) {
    int i0 = q * 1024 + t * 4;
    float4 yv = *(const float4*)&yr[i0];
    uint2 zv = *(const uint2*)&zr[i0];
    float z0 = bf2f((unsigned short)(zv.x & 0xffffu));
    float z1 = bf2f((unsigned short)(zv.x >> 16));
    float z2 = bf2f((unsigned short)(zv.y & 0xffffu));
    float z3 = bf2f((unsigned short)(zv.y >> 16));
    float g0 = yv.x * silu_f(z0), g1 = yv.y * silu_f(z1);
    float g2 = yv.z * silu_f(z2), g3 = yv.w * silu_f(z3);
    g[q * 4 + 0] = g0; g[q * 4 + 1] = g1; g[q * 4 + 2] = g2; g[q * 4 + 3] = g3;
    ss += g0 * g0 + g1 * g1 + g2 * g2 + g3 * g3;
  }
#pragma unroll
  for (int off = 32; off > 0; off >>= 1) ss += __shfl_down(ss, off, 64);
  if ((t & 63) == 0) red[t >> 6] = ss;
  __syncthreads();
  if (t == 0) sc_s = rsqrtf((red[0] + red[1] + red[2] + red[3]) * (1.f / 4096.f) + 1e-5f);
  __syncthreads();
  float sc = sc_s;
#pragma unroll
  for (int q = 0; q < 4; q++) {
    int i0 = q * 1024 + t * 4;
    float nv[4];
    load4(nw, i0, fn, nv);
    unsigned short o0 = f2bf(g[q * 4 + 0] * sc * nv[0]);
    unsigned short o1 = f2bf(g[q * 4 + 1] * sc * nv[1]);
    unsigned short o2 = f2bf(g[q * 4 + 2] * sc * nv[2]);
    unsigned short o3 = f2bf(g[q * 4 + 3] * sc * nv[3]);
    *(uint2*)&yfb[(long long)row * I_SZ + i0] =
        make_uint2((unsigned int)o0 | ((unsigned int)o1 << 16),
                   (unsigned int)o2 | ((unsigned int)o3 << 16));
  }
}

// ---------------------------------------------------------------------------
extern "C" void kernel_launch(void* const* d_in, const int* in_sizes, int n_in,
                              void* d_out, int out_size, void* d_ws, size_t ws_size,
                              hipStream_t stream) {
  const void* hs     = d_in[0];
  const void* W_in   = d_in[1];
  const void* conv_w = d_in[2];
  const void* conv_b = d_in[3];
  const void* dt_b   = d_in[4];
  const void* A_log  = d_in[5];
  const void* Dw     = d_in[6];
  const void* nw     = d_in[7];
  const void* W_out  = d_in[8];

  char* ws = (char*)d_ws;
  size_t off = 0;
  auto alloc = [&](size_t bytes) -> void* {
    void* p = ws + off;
    off += (bytes + 255) & ~(size_t)255;
    return p;
  };
  const long long ML = (long long)B_SZ * L_SZ;  // 4096 rows
  int* flags = (int*)alloc(64);
  unsigned short* proj  = (unsigned short*)alloc(ML * PROJ_SZ * 2);             // 66.5 MB
  unsigned short* convx = (unsigned short*)alloc(ML * CONV_SZ * 2);             // 34 MB
  float* dtv  = (float*)alloc(ML * NH_SZ * 4);                                  // 1 MB
  float* acsb = (float*)alloc((long long)B_SZ * NC_SZ * NH_SZ * CH_SZ * 4);     // 1 MB
  float* Gm   = (float*)alloc((long long)B_SZ * NC_SZ * CH_SZ * CH_SZ * 4);     // 4 MB
  float* stc  = (float*)alloc((long long)B_SZ * NC_SZ * NH_SZ * P_SZ * N_SZ * 4);  // 32 MB
  float* yb   = (float*)alloc(ML * I_SZ * 4);                                   // 64 MB
  unsigned short* yfb = (unsigned short*)stc;  // alias: stc dead after yoff
  // bf16 staging copies alias the yb region (dead until yoff / after norm_k)
  unsigned short* hs_bf   = (unsigned short*)yb;                 // 16 MB
  unsigned short* Win_bf  = (unsigned short*)yb + 8388608;       // 34.9 MB (ends <51MB)
  unsigned short* Wout_bf = (unsigned short*)yb;                 // 16 MB (after norm_k)
  (void)n_in; (void)out_size;
  if (off > ws_size) return;

  dim3 blk(256);
  // 0. per-tensor dtype detection
  detect_k<<<1, blk, 0, stream>>>(hs, W_in, conv_w, conv_b, dt_b, A_log, Dw, nw, W_out,
                                  in_sizes[0], in_sizes[1], in_sizes[2], in_sizes[3],
                                  in_sizes[4], in_sizes[5], in_sizes[6], in_sizes[7],
                                  in_sizes[8], flags);
  // 0a. convert hs, W_in to packed bf16
  cvt_bf16_k<<<dim3(4096), blk, 0, stream>>>(hs, hs_bf, 1048576LL, flags, 0);
  cvt_bf16_k<<<dim3(8512), blk, 0, stream>>>(W_in, Win_bf, 2179072LL, flags, 1);
  // 1. in-proj: proj[4096,8512] = hs @ W_in^T  (bf16 out)
  gemm_8ph_k<<<dim3(512), dim3(512), 0, stream>>>(
      hs_bf, Win_bf, proj, PROJ_SZ, H_SZ, H_SZ, H_SZ, PROJ_SZ, /*gxTiles=*/32);
  gemm_2ph_k<0><<<dim3(96), blk, 0, stream>>>(
      hs_bf, Win_bf + 8192LL * 2048, proj + 8192, 320, H_SZ,
      H_SZ, H_SZ, PROJ_SZ, /*gxTiles=*/3, flags, 15);
  // 2. conv + silu
  conv_silu_k<<<dim3((B_SZ * L_SZ * (CONV_SZ / 4) + 255) / 256), blk, 0, stream>>>(
      proj, conv_w, conv_b, convx, flags);
  // 3. dt
  dt_prep_k<<<dim3((unsigned)(ML * NH_SZ / 256)), blk, 0, stream>>>(proj, dt_b, dtv, flags);
  // 4. cumsum A*dt
  acs_scan_k<<<dim3(B_SZ * NC_SZ * NH_SZ), blk, 0, stream>>>(dtv, A_log, acsb, flags);
  // 5. G = Cc @ Bc^T per (b,chunk)  (MFMA, exact)
  gemm_g_k<<<dim3(2, 2, 16), blk, 0, stream>>>(convx, Gm);
  // 6. per-chunk states
  chunk_states_k<<<dim3(1024), blk, 0, stream>>>(convx, dtv, acsb, stc);
  // 7. inter-chunk recurrence (in-place on stc)
  recur_k<<<dim3(B_SZ * NH_SZ), blk, 0, stream>>>(stc, acsb);
  // 8. Y_off + D*x  (MFMA; overwrites yb; hs_bf/Win_bf dead)
  yoff_mfma_k<<<dim3(1024), blk, 0, stream>>>(convx, stc, acsb, Dw, yb, flags);
  // 9. Y_diag (MFMA)
  ydiag_mfma_k<<<dim3(1024), blk, 0, stream>>>(convx, dtv, acsb, Gm, yb);
  // 10. gated RMSNorm
  norm_k<<<dim3((unsigned)ML), blk, 0, stream>>>(yb, proj, nw, yfb, flags);
  // 10a. convert W_out (yb now dead)
  cvt_bf16_k<<<dim3(4096), blk, 0, stream>>>(W_out, Wout_bf, 1048576LL, flags, 8);
  // 11. out-proj
  gemm_2ph_k<2><<<dim3(512), blk, 0, stream>>>(
      yfb, Wout_bf, d_out, H_SZ, I_SZ, I_SZ, I_SZ, H_SZ, /*gxTiles=*/16,
      flags, 0);
}